// Round 6
// baseline (677.951 us; speedup 1.0000x reference)
//
#include <hip/hip_runtime.h>
#include <hip/hip_bf16.h>

#define HW 65536
#define KPAD 584   // Vt row stride (bf16): 1168B rows, 16B-aligned

typedef __attribute__((ext_vector_type(8))) short bf8;
typedef __attribute__((ext_vector_type(4))) float f4;

__device__ __forceinline__ unsigned short f2b(float x) {   // RNE float->bf16
  unsigned int u = __float_as_uint(x);
  unsigned int r = (u + 0x7fff + ((u >> 16) & 1)) >> 16;
  return (unsigned short)r;
}
__device__ __forceinline__ unsigned int pk2(float lo, float hi) {  // trunc pack 2xbf16
  return (__float_as_uint(hi) & 0xffff0000u) | (__float_as_uint(lo) >> 16);
}

// ================= device bodies =================
__device__ __forceinline__ void stem_front_body(
    int bx, int t, const float* __restrict__ depth,
    const float* __restrict__ cw1, const float* __restrict__ cb1,
    const float* __restrict__ cw2, const float* __restrict__ cb2,
    float* __restrict__ t2) {
  int p = bx * 256 + t;
  int y = p >> 8, x = p & 255;
  float in9[9];
#pragma unroll
  for (int ky = 0; ky < 3; ky++)
#pragma unroll
    for (int kx = 0; kx < 3; kx++) {
      int yy = y + ky - 1, xx = x + kx - 1;
      bool ok = ((unsigned)yy < 256u) && ((unsigned)xx < 256u);
      in9[ky*3+kx] = ok ? depth[yy*256+xx] : 0.f;
    }
  float t1[8];
#pragma unroll
  for (int o = 0; o < 8; o++) {
    float s = cb1[o];
#pragma unroll
    for (int i = 0; i < 9; i++) s += in9[i] * cw1[o*9+i];
    t1[o] = fmaxf(s, 0.f);
  }
#pragma unroll
  for (int o = 0; o < 16; o++) {
    float s = cb2[o];
#pragma unroll
    for (int ci = 0; ci < 8; ci++) s += t1[ci] * cw2[o*8+ci];
    t2[o*HW + p] = fmaxf(s, 0.f);
  }
}

// bias layout per (hd,qt): [kb=key/4][q16][r=key&3] -> f4 loads match S^T C-operand
__device__ __forceinline__ void bias_body(
    int bx, int t, const int* __restrict__ rpi,
    const float* __restrict__ rpb, float* __restrict__ biasT) {
  int idx = bx*256 + t;        // 1152*256 = 294912 exact
  int hd = idx / 147456;
  int rem = idx - hd*147456;
  int qt = rem / 9216;
  int r2 = rem - qt*9216;
  int kb = r2 >> 6;
  int q16 = (r2 >> 2) & 15;
  int r = r2 & 3;
  int key = kb*4 + r;
  int qq = qt*16 + q16;
  biasT[idx] = rpb[rpi[qq*576 + key]*2 + hd] - 8.0f;  // -8 shift cancels in normalize
}

// slabs: 0: q1=LN(x)@wq  1/2: kv1=LN(IN(t4))@wkv lo/hi  3: q2=LN(IN(t4))@wq  4/5: kv2=LN(x)@wkv lo/hi
__device__ __forceinline__ void lnmm_body(
    int slab, int bx, int t,
    float* ws, float* gs, float* bs, float* b2s, float* as, float* bbs,
    const float* __restrict__ x, const float* __restrict__ t4,
    const float* __restrict__ part,
    const float* __restrict__ ig, const float* __restrict__ ib,
    const float* __restrict__ n1g, const float* __restrict__ n1b,
    const float* __restrict__ wq, const float* __restrict__ bq,
    const float* __restrict__ wkv, const float* __restrict__ bkv,
    float* q1, float* kv1, float* q2, float* kv2) {
  const float* src; const float* wm; const float* bo; float* dst;
  int wstride, coff; bool apply_in;
  switch (slab) {
    default:
    case 0: src=x;  wm=wq;  bo=bq;  dst=q1;         wstride=32; coff=0;  apply_in=false; break;
    case 1: src=t4; wm=wkv; bo=bkv; dst=kv1;        wstride=64; coff=0;  apply_in=true;  break;
    case 2: src=t4; wm=wkv; bo=bkv; dst=kv1+32*HW;  wstride=64; coff=32; apply_in=true;  break;
    case 3: src=t4; wm=wq;  bo=bq;  dst=q2;         wstride=32; coff=0;  apply_in=true;  break;
    case 4: src=x;  wm=wkv; bo=bkv; dst=kv2;        wstride=64; coff=0;  apply_in=false; break;
    case 5: src=x;  wm=wkv; bo=bkv; dst=kv2+32*HW;  wstride=64; coff=32; apply_in=false; break;
  }
  for (int i = t; i < 1024; i += 256) ws[i] = wm[(i>>5)*wstride + coff + (i&31)];
  if (t < 32) {
    gs[t] = n1g[t]; bs[t] = n1b[t]; b2s[t] = bo[coff+t];
    if (apply_in) {            // inline stats finalize from part[]
      float s = 0.f, ss = 0.f;
#pragma unroll
      for (int k = 0; k < 16; k++) { s += part[t*16+k]; ss += part[512 + t*16+k]; }
      float m = s * (1.f/65536.f);
      float var = ss * (1.f/65536.f) - m*m;
      float a = rsqrtf(var + 1e-5f) * ig[t];
      as[t] = a; bbs[t] = ib[t] - m*a;
    }
  }
  __syncthreads();
  int p = bx*256 + t;
  float v[32]; float s = 0.f;
  if (apply_in) {
#pragma unroll
    for (int c = 0; c < 32; c++) { v[c] = src[c*HW+p]*as[c] + bbs[c]; s += v[c]; }
  } else {
#pragma unroll
    for (int c = 0; c < 32; c++) { v[c] = src[c*HW+p]; s += v[c]; }
  }
  float m = s * 0.03125f;
  float ss = 0.f;
#pragma unroll
  for (int c = 0; c < 32; c++) { float d = v[c]-m; ss += d*d; }
  float rs = rsqrtf(ss*0.03125f + 1e-5f);
  float acc[32];
#pragma unroll
  for (int j = 0; j < 32; j++) acc[j] = b2s[j];
#pragma unroll
  for (int c = 0; c < 32; c++) {
    float ln = (v[c]-m)*rs*gs[c] + bs[c];
    const float4* w4 = (const float4*)&ws[c*32];
#pragma unroll
    for (int j4 = 0; j4 < 8; j4++) {
      float4 w = w4[j4];
      acc[j4*4+0] += ln*w.x; acc[j4*4+1] += ln*w.y;
      acc[j4*4+2] += ln*w.z; acc[j4*4+3] += ln*w.w;
    }
  }
#pragma unroll
  for (int j = 0; j < 32; j++) dst[j*HW+p] = acc[j];
}

// ================= kernels =================
// mega-launch: y=0 stem_front (256) | y=1 bias (1152) | y=2..4 lnmm slabs {0,4,5} (256 each)
__global__ __launch_bounds__(256) void k_misc(
    const float* __restrict__ depth,
    const float* __restrict__ cw1, const float* __restrict__ cb1,
    const float* __restrict__ cw2, const float* __restrict__ cb2,
    float* __restrict__ t2,
    const int* __restrict__ rpi, const float* __restrict__ rpb, float* __restrict__ biasT,
    const float* __restrict__ x, const float* __restrict__ t4, const float* __restrict__ part,
    const float* __restrict__ ig, const float* __restrict__ ib,
    const float* __restrict__ n1g, const float* __restrict__ n1b,
    const float* __restrict__ wq, const float* __restrict__ bq,
    const float* __restrict__ wkv, const float* __restrict__ bkv,
    float* q1, float* kv1, float* q2, float* kv2) {
  __shared__ __align__(16) float ws[1024];
  __shared__ float gs[32], bs[32], b2s[32], as[32], bbs[32];
  int role = blockIdx.y, t = threadIdx.x, bx = blockIdx.x;
  if (role == 0) { if (bx < 256) stem_front_body(bx, t, depth, cw1, cb1, cw2, cb2, t2); return; }
  if (role == 1) { bias_body(bx, t, rpi, rpb, biasT); return; }
  if (bx >= 256) return;
  int slab = (role == 2) ? 0 : role + 1;   // 2->0, 3->4, 4->5
  lnmm_body(slab, bx, t, ws, gs, bs, b2s, as, bbs,
            x, t4, part, ig, ib, n1g, n1b, wq, bq, wkv, bkv, q1, kv1, q2, kv2);
}

__global__ __launch_bounds__(256) void k_lnmm3(
    const float* __restrict__ x, const float* __restrict__ t4, const float* __restrict__ part,
    const float* __restrict__ ig, const float* __restrict__ ib,
    const float* __restrict__ n1g, const float* __restrict__ n1b,
    const float* __restrict__ wq, const float* __restrict__ bq,
    const float* __restrict__ wkv, const float* __restrict__ bkv,
    float* q1, float* kv1, float* q2, float* kv2, int ybase) {
  __shared__ __align__(16) float ws[1024];
  __shared__ float gs[32], bs[32], b2s[32], as[32], bbs[32];
  lnmm_body(ybase + blockIdx.y, blockIdx.x, threadIdx.x, ws, gs, bs, b2s, as, bbs,
            x, t4, part, ig, ib, n1g, n1b, wq, bq, wkv, bkv, q1, kv1, q2, kv2);
}

__global__ __launch_bounds__(256) void k_conv3(
    const float* __restrict__ t2, const float* __restrict__ cw3,
    const float* __restrict__ cb3, float* __restrict__ t3) {
  int t = threadIdx.x;
  int p = blockIdx.x*256 + t;
  int og = blockIdx.y;
  int y = p >> 8, x = p & 255;
  float acc[4];
#pragma unroll
  for (int o = 0; o < 4; o++) acc[o] = cb3[og*4+o];
#pragma unroll 1
  for (int tap = 0; tap < 9; tap++) {
    int ky = tap/3 - 1, kx = tap - (tap/3)*3 - 1;
    int yy = y+ky, xx = x+kx;
    bool ok = ((unsigned)yy < 256u) && ((unsigned)xx < 256u);
    int pp = yy*256+xx;
#pragma unroll
    for (int ci = 0; ci < 16; ci++) {
      float v = ok ? t2[ci*HW+pp] : 0.f;
#pragma unroll
      for (int o = 0; o < 4; o++)
        acc[o] += v * cw3[(og*4+o)*144 + ci*9 + tap];   // uniform -> s_load
    }
  }
#pragma unroll
  for (int o = 0; o < 4; o++) t3[(og*4+o)*HW+p] = fmaxf(acc[o], 0.f);
}

__global__ __launch_bounds__(256) void k_conv4(
    const float* __restrict__ t3, const float* __restrict__ cw4,
    const float* __restrict__ cb4, float* __restrict__ t4) {
  int t = threadIdx.x;
  int p = blockIdx.x*256 + t;
  float v[16];
#pragma unroll
  for (int ci = 0; ci < 16; ci++) v[ci] = t3[ci*HW+p];
#pragma unroll
  for (int o = 0; o < 32; o++) {
    float s = cb4[o];
#pragma unroll
    for (int ci = 0; ci < 16; ci++) s += v[ci]*cw4[o*16+ci];
    t4[o*HW+p] = s;
  }
}

__global__ __launch_bounds__(256) void k_instats1(const float* __restrict__ t4,
                                                  float* __restrict__ part) {
  int c = blockIdx.x >> 4, seg = blockIdx.x & 15;   // 512 blocks
  const float4* src = (const float4*)(t4 + c*HW + seg*4096);
  float s = 0.f, ss = 0.f;
  for (int i = threadIdx.x; i < 1024; i += 256) {
    float4 v = src[i];
    s  += v.x + v.y + v.z + v.w;
    ss += v.x*v.x + v.y*v.y + v.z*v.z + v.w*v.w;
  }
#pragma unroll
  for (int off = 32; off > 0; off >>= 1) {
    s  += __shfl_down(s, off, 64);
    ss += __shfl_down(ss, off, 64);
  }
  __shared__ float sh[8];
  int wid = threadIdx.x >> 6;
  if ((threadIdx.x & 63) == 0) { sh[wid] = s; sh[4+wid] = ss; }
  __syncthreads();
  if (threadIdx.x == 0) {
    part[blockIdx.x]       = sh[0]+sh[1]+sh[2]+sh[3];
    part[512 + blockIdx.x] = sh[4]+sh[5]+sh[6]+sh[7];
  }
}

// ---------------- MFMA attention, S^T formulation (no P LDS round-trip) ----------------
__global__ __launch_bounds__(256) void k_attn(
    const float* __restrict__ qA, const float* __restrict__ kvA, float* __restrict__ aoA,
    const float* __restrict__ qB, const float* __restrict__ kvB, float* __restrict__ aoB,
    const float* __restrict__ biasT) {
  __shared__ __align__(16) unsigned short Qs[256*16];   // [q][d]
  __shared__ __align__(16) unsigned short Ks[576*16];   // [key][d]
  __shared__ __align__(16) unsigned short Vt[16*KPAD];  // [d][key-permuted]

  const float* q  = blockIdx.y ? qB  : qA;
  const float* kv = blockIdx.y ? kvB : kvA;
  float* ao       = blockIdx.y ? aoB : aoA;

  int wi = blockIdx.x >> 1, hd = blockIdx.x & 1;
  int wy = wi >> 4, wx = wi & 15;
  int t = threadIdx.x;
  int by = wy*16 - 4, bx = wx*16 - 4;
  int kbase = hd*16*HW, vbase = (32 + hd*16)*HW;

  {
    int qy = wy*16 + (t >> 4), qx = wx*16 + (t & 15);
    int p = qy*256 + qx;
    unsigned short tmp[16];
#pragma unroll
    for (int i = 0; i < 16; i++) tmp[i] = f2b(q[(hd*16+i)*HW + p] * 0.25f);
    *(uint4*)&Qs[t*16]     = *(uint4*)&tmp[0];
    *(uint4*)&Qs[t*16 + 8] = *(uint4*)&tmp[8];
  }
  for (int e = t; e < 576; e += 256) {
    int dy = e / 24, dx = e - dy*24;
    int yy = by + dy, xx = bx + dx;
    bool ok = ((unsigned)yy < 256u) && ((unsigned)xx < 256u);
    int pp = yy*256 + xx;
    // V permuted within each 32-key block: ppos = q4*8 + half*4 + r  (matches PV A-slot order)
    int off = e & 31;
    int ppos = ((off & 12) << 1) + ((off >> 4) << 2) + (off & 3);
    int vcol = (e & ~31) + ppos;
    unsigned short tk[16];
#pragma unroll
    for (int i = 0; i < 16; i++) {
      float kvl = ok ? kv[kbase + i*HW + pp] : 0.f;
      float vvl = ok ? kv[vbase + i*HW + pp] : 0.f;
      tk[i] = f2b(kvl);
      Vt[i*KPAD + vcol] = f2b(vvl);
    }
    *(uint4*)&Ks[e*16]     = *(uint4*)&tk[0];
    *(uint4*)&Ks[e*16 + 8] = *(uint4*)&tk[8];
  }
  __syncthreads();

  int wave = t >> 6, lane = t & 63;
  int quad = lane >> 4, l16 = lane & 15;
  const bf8 zero8 = {0,0,0,0,0,0,0,0};

#pragma unroll 1
  for (int pp2 = 0; pp2 < 2; pp2++) {
    int qta = wave*4 + pp2*2, qtb = qta + 1;   // two q-tiles in flight (ILP)
    bf8 qfa = zero8, qfb = zero8;
    if (quad < 2) {
      qfa = *(const bf8*)&Qs[(qta*16 + l16)*16 + quad*8];
      qfb = *(const bf8*)&Qs[(qtb*16 + l16)*16 + quad*8];
    }
    f4 oa = {0.f,0.f,0.f,0.f}, ob = {0.f,0.f,0.f,0.f};
    float la = 0.f, lb = 0.f;
    const float* bba = biasT + (hd*16 + qta)*9216 + quad*64 + l16*4;
    const float* bbb = biasT + (hd*16 + qtb)*9216 + quad*64 + l16*4;
    f4 ba0 = *(const f4*)&bba[0];
    f4 ba1 = *(const f4*)&bba[256];
    f4 bb0 = *(const f4*)&bbb[0];
    f4 bb1 = *(const f4*)&bbb[256];

#pragma unroll 2
    for (int kt2 = 0; kt2 < 18; kt2++) {
      int k0 = kt2 * 32;
      // prefetch next k-step bias (last iter reads into part[] region -- harmless, in-ws)
      f4 na0 = *(const f4*)&bba[(k0+32)*16];
      f4 na1 = *(const f4*)&bba[(k0+48)*16];
      f4 nb0 = *(const f4*)&bbb[(k0+32)*16];
      f4 nb1 = *(const f4*)&bbb[(k0+48)*16];
      bf8 kf0 = zero8, kf1 = zero8;
      if (quad < 2) {
        kf0 = *(const bf8*)&Ks[(k0 + l16)*16 + quad*8];
        kf1 = *(const bf8*)&Ks[(k0 + 16 + l16)*16 + quad*8];
      }
      // S^T = K·Q^T + bias^T : lane holds (key=k0(+16)+quad*4+r, q=l16)
      f4 sa0 = __builtin_amdgcn_mfma_f32_16x16x32_bf16(kf0, qfa, ba0, 0, 0, 0);
      f4 sa1 = __builtin_amdgcn_mfma_f32_16x16x32_bf16(kf1, qfa, ba1, 0, 0, 0);
      f4 sb0 = __builtin_amdgcn_mfma_f32_16x16x32_bf16(kf0, qfb, bb0, 0, 0, 0);
      f4 sb1 = __builtin_amdgcn_mfma_f32_16x16x32_bf16(kf1, qfb, bb1, 0, 0, 0);
      float pa0[4], pa1[4], pb0[4], pb1[4];
#pragma unroll
      for (int r = 0; r < 4; r++) {
        pa0[r] = __expf(sa0[r]); pa1[r] = __expf(sa1[r]);
        pb0[r] = __expf(sb0[r]); pb1[r] = __expf(sb1[r]);
        la += pa0[r] + pa1[r];
        lb += pb0[r] + pb1[r];
      }
      // P^T C-layout == PV A-layout: pack in registers (bf16 truncation)
      union { unsigned int u[4]; bf8 v; } Pa, Pb;
      Pa.u[0] = pk2(pa0[0], pa0[1]); Pa.u[1] = pk2(pa0[2], pa0[3]);
      Pa.u[2] = pk2(pa1[0], pa1[1]); Pa.u[3] = pk2(pa1[2], pa1[3]);
      Pb.u[0] = pk2(pb0[0], pb0[1]); Pb.u[1] = pk2(pb0[2], pb0[3]);
      Pb.u[2] = pk2(pb1[0], pb1[1]); Pb.u[3] = pk2(pb1[2], pb1[3]);
      bf8 vf = *(const bf8*)&Vt[l16*KPAD + k0 + quad*8];   // permuted slots match A
      oa = __builtin_amdgcn_mfma_f32_16x16x32_bf16(Pa.v, vf, oa, 0, 0, 0);
      ob = __builtin_amdgcn_mfma_f32_16x16x32_bf16(Pb.v, vf, ob, 0, 0, 0);
      ba0 = na0; ba1 = na1; bb0 = nb0; bb1 = nb1;
    }
    // l: sum over keys -> reduce across quads (keys split over quads), q = l16
    la += __shfl_xor(la, 16, 64); la += __shfl_xor(la, 32, 64);
    lb += __shfl_xor(lb, 16, 64); lb += __shfl_xor(lb, 32, 64);
#pragma unroll
    for (int r = 0; r < 4; r++) {
      float lva = __shfl(la, quad*4 + r, 64);   // l for q=quad*4+r
      float lvb = __shfl(lb, quad*4 + r, 64);
      int qwa = qta*16 + quad*4 + r;
      int qwb = qtb*16 + quad*4 + r;
      ao[(hd*16 + l16)*HW + (wy*16 + (qwa >> 4))*256 + wx*16 + (qwa & 15)] = oa[r] / lva;
      ao[(hd*16 + l16)*HW + (wy*16 + (qwb >> 4))*256 + wx*16 + (qwb & 15)] = ob[r] / lvb;
    }
  }
}

// ---------------- fused: proj+shortcut+LN+MLP for BOTH ocabs, + final sum -> out ----------------
__global__ __launch_bounds__(256) void k_projmlpfinal(
    const float* __restrict__ ao1, const float* __restrict__ ao2,
    const float* __restrict__ x, const float* __restrict__ t4,
    const float* __restrict__ part,
    const float* __restrict__ ig, const float* __restrict__ ib,
    const float* __restrict__ wp, const float* __restrict__ bp,
    const float* __restrict__ n2g, const float* __restrict__ n2b,
    const float* __restrict__ mw1, const float* __restrict__ mb1,
    const float* __restrict__ mw2, const float* __restrict__ mb2,
    float* __restrict__ out) {
  __shared__ __align__(16) float wps[1024];
  __shared__ __align__(16) float w1s[2048];
  __shared__ __align__(16) float w2s[2048];
  __shared__ float bps[32], b1s[64], b2s[32], gs[32], bs[32], as[32], bbs[32];
  int t = threadIdx.x;
  for (int i = t; i < 1024; i += 256) wps[i] = wp[i];
  for (int i = t; i < 2048; i += 256) { w1s[i] = mw1[i]; w2s[i] = mw2[i]; }
  if (t < 64) b1s[t] = mb1[t];
  if (t < 32) {
    bps[t] = bp[t]; b2s[t] = mb2[t]; gs[t] = n2g[t]; bs[t] = n2b[t];
    float s = 0.f, ss = 0.f;
#pragma unroll
    for (int k = 0; k < 16; k++) { s += part[t*16+k]; ss += part[512 + t*16+k]; }
    float m = s * (1.f/65536.f);
    float var = ss * (1.f/65536.f) - m*m;
    float a = rsqrtf(var + 1e-5f) * ig[t];
    as[t] = a; bbs[t] = ib[t] - m*a;
  }
  __syncthreads();
  int p = blockIdx.x*256 + t;
  float tot[32];
#pragma unroll 1
  for (int oc = 0; oc < 2; oc++) {
    const float* ao = oc ? ao2 : ao1;
    float acc[32];
#pragma unroll
    for (int j = 0; j < 32; j++) acc[j] = bps[j];
#pragma unroll
    for (int c = 0; c < 32; c++) {
      float vc = ao[c*HW+p];
      const float4* w4 = (const float4*)&wps[c*32];
#pragma unroll
      for (int j4 = 0; j4 < 8; j4++) {
        float4 w = w4[j4];
        acc[j4*4+0] += vc*w.x; acc[j4*4+1] += vc*w.y;
        acc[j4*4+2] += vc*w.z; acc[j4*4+3] += vc*w.w;
      }
    }
    if (oc == 0) {
#pragma unroll
      for (int j = 0; j < 32; j++) acc[j] += x[j*HW+p];
    } else {
#pragma unroll
      for (int j = 0; j < 32; j++) acc[j] += t4[j*HW+p]*as[j] + bbs[j];
    }
    float s = 0.f;
#pragma unroll
    for (int j = 0; j < 32; j++) s += acc[j];
    float m = s * 0.03125f;
    float ss = 0.f;
#pragma unroll
    for (int j = 0; j < 32; j++) { float d = acc[j]-m; ss += d*d; }
    float rs = rsqrtf(ss*0.03125f + 1e-5f);
    float r[32];
#pragma unroll
    for (int j = 0; j < 32; j++) r[j] = b2s[j];
#pragma unroll 1
    for (int half = 0; half < 2; half++) {
      float h[32];
#pragma unroll
      for (int k = 0; k < 32; k++) h[k] = b1s[half*32 + k];
#pragma unroll
      for (int c = 0; c < 32; c++) {
        float ln = (acc[c] - m) * rs * gs[c] + bs[c];
        const float4* w4 = (const float4*)&w1s[c*64 + half*32];
#pragma unroll
        for (int k4 = 0; k4 < 8; k4++) {
          float4 w = w4[k4];
          h[k4*4+0] += ln*w.x; h[k4*4+1] += ln*w.y; h[k4*4+2] += ln*w.z; h[k4*4+3] += ln*w.w;
        }
      }
#pragma unroll
      for (int k = 0; k < 32; k++) {
        float xx = h[k];
        float u = 0.7978845608f * (xx + 0.044715f*xx*xx*xx);
        float th = 1.f - 2.f/(1.f + __expf(2.f*u));
        h[k] = 0.5f * xx * (1.f + th);
      }
#pragma unroll
      for (int k = 0; k < 32; k++) {
        float hk = h[k];
        const float4* w4 = (const float4*)&w2s[(half*32 + k)*32];
#pragma unroll
        for (int j4 = 0; j4 < 8; j4++) {
          float4 w = w4[j4];
          r[j4*4+0] += hk*w.x; r[j4*4+1] += hk*w.y; r[j4*4+2] += hk*w.z; r[j4*4+3] += hk*w.w;
        }
      }
    }
    if (oc == 0) {
#pragma unroll
      for (int j = 0; j < 32; j++) tot[j] = acc[j] + r[j];
    } else {
#pragma unroll
      for (int j = 0; j < 32; j++) tot[j] += acc[j] + r[j];
    }
  }
#pragma unroll
  for (int j = 0; j < 32; j++) out[j*HW + p] = tot[j] + x[j*HW+p];
}

extern "C" void kernel_launch(void* const* d_in, const int* in_sizes, int n_in,
                              void* d_out, int out_size, void* d_ws, size_t ws_size,
                              hipStream_t stream) {
  const float* x    = (const float*)d_in[0];
  const float* depth= (const float*)d_in[1];
  const int*   rpi  = (const int*)d_in[2];
  const float* cw1  = (const float*)d_in[3],  *cb1 = (const float*)d_in[4];
  const float* cw2  = (const float*)d_in[5],  *cb2 = (const float*)d_in[6];
  const float* cw3  = (const float*)d_in[7],  *cb3 = (const float*)d_in[8];
  const float* cw4  = (const float*)d_in[9],  *cb4 = (const float*)d_in[10];
  const float* in_g = (const float*)d_in[11], *in_b = (const float*)d_in[12];
  const float* n1g  = (const float*)d_in[13], *n1b = (const float*)d_in[14];
  const float* wq   = (const float*)d_in[15], *bq  = (const float*)d_in[16];
  const float* wkv  = (const float*)d_in[17], *bkv = (const float*)d_in[18];
  const float* rpb  = (const float*)d_in[19];
  const float* wp   = (const float*)d_in[20], *bp  = (const float*)d_in[21];
  const float* n2g  = (const float*)d_in[22], *n2b = (const float*)d_in[23];
  const float* mw1  = (const float*)d_in[24], *mb1 = (const float*)d_in[25];
  const float* mw2  = (const float*)d_in[26], *mb2 = (const float*)d_in[27];

  float* W   = (float*)d_ws;
  float* out = (float*)d_out;

  bool big = ws_size >= (size_t)76800000;   // merged path needs ~76.7 MB

  if (big) {
    float* t4    = W;                    // 2M floats
    float* q1    = W + 2097152;
    float* q2    = W + 4194304;          // t3 aliases first 1M
    float* kv1   = W + 6291456;          // 4M
    float* kv2   = W + 10485760;         // 4M
    float* ao1   = W + 14680064;         // t2 aliases first 1M
    float* ao2   = W + 16777216;
    float* biasT = W + 18874368;         // 294912
    float* part  = W + 19169280;         // 1024
    float* t2 = ao1, *t3 = q2;

    k_misc   <<<dim3(1152,5), 256, 0, stream>>>(depth, cw1, cb1, cw2, cb2, t2,
                                                rpi, rpb, biasT,
                                                x, t4, part, in_g, in_b, n1g, n1b,
                                                wq, bq, wkv, bkv, q1, kv1, q2, kv2);
    k_conv3  <<<dim3(256,4), 256, 0, stream>>>(t2, cw3, cb3, t3);
    k_conv4  <<<256, 256, 0, stream>>>(t3, cw4, cb4, t4);
    k_instats1<<<512, 256, 0, stream>>>(t4, part);
    k_lnmm3  <<<dim3(256,3), 256, 0, stream>>>(x, t4, part, in_g, in_b, n1g, n1b,
                                               wq, bq, wkv, bkv, q1, kv1, q2, kv2, 1);
    k_attn   <<<dim3(512,2), 256, 0, stream>>>(q1, kv1, ao1, q2, kv2, ao2, biasT);
    k_projmlpfinal<<<256, 256, 0, stream>>>(ao1, ao2, x, t4, part, in_g, in_b,
                                            wp, bp, n2g, n2b, mw1, mb1, mw2, mb2, out);
  } else {
    // serial fallback, ~51.5 MB
    float* t4    = W;
    float* q1    = W + 2097152;
    float* kv1   = W + 4194304;          // 4M
    float* ao1   = W + 8388608;          // t2 aliases first 1M
    float* ao2   = W + 10485760;         // t3 aliases first 1M
    float* biasT = W + 12582912;
    float* part  = W + 12877824;
    float* t2 = ao1, *t3 = ao2;

    k_misc   <<<dim3(1152,2), 256, 0, stream>>>(depth, cw1, cb1, cw2, cb2, t2,
                                                rpi, rpb, biasT,
                                                x, t4, part, in_g, in_b, n1g, n1b,
                                                wq, bq, wkv, bkv, q1, kv1, q1, kv1);
    k_conv3  <<<dim3(256,4), 256, 0, stream>>>(t2, cw3, cb3, t3);
    k_conv4  <<<256, 256, 0, stream>>>(t3, cw4, cb4, t4);
    k_instats1<<<512, 256, 0, stream>>>(t4, part);
    k_lnmm3  <<<dim3(256,3), 256, 0, stream>>>(x, t4, part, in_g, in_b, n1g, n1b,
                                               wq, bq, wkv, bkv, q1, kv1, q1, kv1, 0);
    k_attn   <<<dim3(512,1), 256, 0, stream>>>(q1, kv1, ao1, q1, kv1, ao1, biasT);
    k_lnmm3  <<<dim3(256,3), 256, 0, stream>>>(x, t4, part, in_g, in_b, n1g, n1b,
                                               wq, bq, wkv, bkv, q1, kv1, q1, kv1, 3);
    k_attn   <<<dim3(512,1), 256, 0, stream>>>(q1, kv1, ao2, q1, kv1, ao2, biasT);
    k_projmlpfinal<<<256, 256, 0, stream>>>(ao1, ao2, x, t4, part, in_g, in_b,
                                            wp, bp, n2g, n2b, mw1, mb1, mw2, mb2, out);
  }
}

// Round 7
// 296.471 us; speedup vs baseline: 2.2867x; 2.2867x over previous
//
#include <hip/hip_runtime.h>
#include <hip/hip_bf16.h>

#define HW 65536
#define KPAD 584   // Vt row stride (bf16): 1168B rows, 16B-aligned

typedef __attribute__((ext_vector_type(8))) short bf8;
typedef __attribute__((ext_vector_type(4))) float f4;

__device__ __forceinline__ unsigned short f2b(float x) {   // RNE float->bf16
  unsigned int u = __float_as_uint(x);
  unsigned int r = (u + 0x7fff + ((u >> 16) & 1)) >> 16;
  return (unsigned short)r;
}
__device__ __forceinline__ unsigned int pk2(float lo, float hi) {  // trunc pack 2xbf16
  return (__float_as_uint(hi) & 0xffff0000u) | (__float_as_uint(lo) >> 16);
}

// ================= device bodies =================
__device__ __forceinline__ void stem_front_body(
    int bx, int t, const float* __restrict__ depth,
    const float* __restrict__ cw1, const float* __restrict__ cb1,
    const float* __restrict__ cw2, const float* __restrict__ cb2,
    float* __restrict__ t2) {
  int p = bx * 256 + t;
  int y = p >> 8, x = p & 255;
  float in9[9];
#pragma unroll
  for (int ky = 0; ky < 3; ky++)
#pragma unroll
    for (int kx = 0; kx < 3; kx++) {
      int yy = y + ky - 1, xx = x + kx - 1;
      bool ok = ((unsigned)yy < 256u) && ((unsigned)xx < 256u);
      in9[ky*3+kx] = ok ? depth[yy*256+xx] : 0.f;
    }
  float t1[8];
#pragma unroll
  for (int o = 0; o < 8; o++) {
    float s = cb1[o];
#pragma unroll
    for (int i = 0; i < 9; i++) s += in9[i] * cw1[o*9+i];
    t1[o] = fmaxf(s, 0.f);
  }
#pragma unroll
  for (int o = 0; o < 16; o++) {
    float s = cb2[o];
#pragma unroll
    for (int ci = 0; ci < 8; ci++) s += t1[ci] * cw2[o*8+ci];
    t2[o*HW + p] = fmaxf(s, 0.f);
  }
}

// bias layout per (hd,qt): [kb=key/4][q16][r=key&3] -> f4 loads match S^T C-operand
__device__ __forceinline__ void bias_body(
    int bx, int t, const int* __restrict__ rpi,
    const float* __restrict__ rpb, float* __restrict__ biasT) {
  int idx = bx*256 + t;        // 1152*256 = 294912 exact
  int hd = idx / 147456;
  int rem = idx - hd*147456;
  int qt = rem / 9216;
  int r2 = rem - qt*9216;
  int kb = r2 >> 6;
  int q16 = (r2 >> 2) & 15;
  int r = r2 & 3;
  int key = kb*4 + r;
  int qq = qt*16 + q16;
  biasT[idx] = rpb[rpi[qq*576 + key]*2 + hd] - 8.0f;  // -8 shift cancels in normalize
}

// slabs: 0: q1=LN(x)@wq  1/2: kv1=LN(IN(t4))@wkv lo/hi  3: q2=LN(IN(t4))@wq  4/5: kv2=LN(x)@wkv lo/hi
__device__ __forceinline__ void lnmm_body(
    int slab, int bx, int t,
    float* ws, float* gs, float* bs, float* b2s, float* as, float* bbs,
    const float* __restrict__ x, const float* __restrict__ t4,
    const float* __restrict__ part,
    const float* __restrict__ ig, const float* __restrict__ ib,
    const float* __restrict__ n1g, const float* __restrict__ n1b,
    const float* __restrict__ wq, const float* __restrict__ bq,
    const float* __restrict__ wkv, const float* __restrict__ bkv,
    float* q1, float* kv1, float* q2, float* kv2) {
  const float* src; const float* wm; const float* bo; float* dst;
  int wstride, coff; bool apply_in;
  switch (slab) {
    default:
    case 0: src=x;  wm=wq;  bo=bq;  dst=q1;         wstride=32; coff=0;  apply_in=false; break;
    case 1: src=t4; wm=wkv; bo=bkv; dst=kv1;        wstride=64; coff=0;  apply_in=true;  break;
    case 2: src=t4; wm=wkv; bo=bkv; dst=kv1+32*HW;  wstride=64; coff=32; apply_in=true;  break;
    case 3: src=t4; wm=wq;  bo=bq;  dst=q2;         wstride=32; coff=0;  apply_in=true;  break;
    case 4: src=x;  wm=wkv; bo=bkv; dst=kv2;        wstride=64; coff=0;  apply_in=false; break;
    case 5: src=x;  wm=wkv; bo=bkv; dst=kv2+32*HW;  wstride=64; coff=32; apply_in=false; break;
  }
  for (int i = t; i < 1024; i += 256) ws[i] = wm[(i>>5)*wstride + coff + (i&31)];
  if (t < 32) {
    gs[t] = n1g[t]; bs[t] = n1b[t]; b2s[t] = bo[coff+t];
    if (apply_in) {            // inline stats finalize from part[]
      float s = 0.f, ss = 0.f;
#pragma unroll
      for (int k = 0; k < 16; k++) { s += part[t*16+k]; ss += part[512 + t*16+k]; }
      float m = s * (1.f/65536.f);
      float var = ss * (1.f/65536.f) - m*m;
      float a = rsqrtf(var + 1e-5f) * ig[t];
      as[t] = a; bbs[t] = ib[t] - m*a;
    }
  }
  __syncthreads();
  int p = bx*256 + t;
  float v[32]; float s = 0.f;
  if (apply_in) {
#pragma unroll
    for (int c = 0; c < 32; c++) { v[c] = src[c*HW+p]*as[c] + bbs[c]; s += v[c]; }
  } else {
#pragma unroll
    for (int c = 0; c < 32; c++) { v[c] = src[c*HW+p]; s += v[c]; }
  }
  float m = s * 0.03125f;
  float ss = 0.f;
#pragma unroll
  for (int c = 0; c < 32; c++) { float d = v[c]-m; ss += d*d; }
  float rs = rsqrtf(ss*0.03125f + 1e-5f);
  float acc[32];
#pragma unroll
  for (int j = 0; j < 32; j++) acc[j] = b2s[j];
#pragma unroll
  for (int c = 0; c < 32; c++) {
    float ln = (v[c]-m)*rs*gs[c] + bs[c];
    const float4* w4 = (const float4*)&ws[c*32];
#pragma unroll
    for (int j4 = 0; j4 < 8; j4++) {
      float4 w = w4[j4];
      acc[j4*4+0] += ln*w.x; acc[j4*4+1] += ln*w.y;
      acc[j4*4+2] += ln*w.z; acc[j4*4+3] += ln*w.w;
    }
  }
#pragma unroll
  for (int j = 0; j < 32; j++) dst[j*HW+p] = acc[j];
}

// ================= kernels =================
// mega-launch: y=0 stem_front (256) | y=1 bias (1152) | y=2..4 lnmm slabs {0,4,5} (256 each)
__global__ __launch_bounds__(256) void k_misc(
    const float* __restrict__ depth,
    const float* __restrict__ cw1, const float* __restrict__ cb1,
    const float* __restrict__ cw2, const float* __restrict__ cb2,
    float* __restrict__ t2,
    const int* __restrict__ rpi, const float* __restrict__ rpb, float* __restrict__ biasT,
    const float* __restrict__ x, const float* __restrict__ t4, const float* __restrict__ part,
    const float* __restrict__ ig, const float* __restrict__ ib,
    const float* __restrict__ n1g, const float* __restrict__ n1b,
    const float* __restrict__ wq, const float* __restrict__ bq,
    const float* __restrict__ wkv, const float* __restrict__ bkv,
    float* q1, float* kv1, float* q2, float* kv2) {
  __shared__ __align__(16) float ws[1024];
  __shared__ float gs[32], bs[32], b2s[32], as[32], bbs[32];
  int role = blockIdx.y, t = threadIdx.x, bx = blockIdx.x;
  if (role == 0) { if (bx < 256) stem_front_body(bx, t, depth, cw1, cb1, cw2, cb2, t2); return; }
  if (role == 1) { bias_body(bx, t, rpi, rpb, biasT); return; }
  if (bx >= 256) return;
  int slab = (role == 2) ? 0 : role + 1;   // 2->0, 3->4, 4->5
  lnmm_body(slab, bx, t, ws, gs, bs, b2s, as, bbs,
            x, t4, part, ig, ib, n1g, n1b, wq, bq, wkv, bkv, q1, kv1, q2, kv2);
}

__global__ __launch_bounds__(256) void k_lnmm3(
    const float* __restrict__ x, const float* __restrict__ t4, const float* __restrict__ part,
    const float* __restrict__ ig, const float* __restrict__ ib,
    const float* __restrict__ n1g, const float* __restrict__ n1b,
    const float* __restrict__ wq, const float* __restrict__ bq,
    const float* __restrict__ wkv, const float* __restrict__ bkv,
    float* q1, float* kv1, float* q2, float* kv2, int ybase) {
  __shared__ __align__(16) float ws[1024];
  __shared__ float gs[32], bs[32], b2s[32], as[32], bbs[32];
  lnmm_body(ybase + blockIdx.y, blockIdx.x, threadIdx.x, ws, gs, bs, b2s, as, bbs,
            x, t4, part, ig, ib, n1g, n1b, wq, bq, wkv, bkv, q1, kv1, q2, kv2);
}

__global__ __launch_bounds__(256) void k_conv3(
    const float* __restrict__ t2, const float* __restrict__ cw3,
    const float* __restrict__ cb3, float* __restrict__ t3) {
  int t = threadIdx.x;
  int p = blockIdx.x*256 + t;
  int og = blockIdx.y;
  int y = p >> 8, x = p & 255;
  float acc[4];
#pragma unroll
  for (int o = 0; o < 4; o++) acc[o] = cb3[og*4+o];
#pragma unroll 1
  for (int tap = 0; tap < 9; tap++) {
    int ky = tap/3 - 1, kx = tap - (tap/3)*3 - 1;
    int yy = y+ky, xx = x+kx;
    bool ok = ((unsigned)yy < 256u) && ((unsigned)xx < 256u);
    int pp = yy*256+xx;
#pragma unroll
    for (int ci = 0; ci < 16; ci++) {
      float v = ok ? t2[ci*HW+pp] : 0.f;
#pragma unroll
      for (int o = 0; o < 4; o++)
        acc[o] += v * cw3[(og*4+o)*144 + ci*9 + tap];   // uniform -> s_load
    }
  }
#pragma unroll
  for (int o = 0; o < 4; o++) t3[(og*4+o)*HW+p] = fmaxf(acc[o], 0.f);
}

__global__ __launch_bounds__(256) void k_conv4(
    const float* __restrict__ t3, const float* __restrict__ cw4,
    const float* __restrict__ cb4, float* __restrict__ t4) {
  int t = threadIdx.x;
  int p = blockIdx.x*256 + t;
  float v[16];
#pragma unroll
  for (int ci = 0; ci < 16; ci++) v[ci] = t3[ci*HW+p];
#pragma unroll
  for (int o = 0; o < 32; o++) {
    float s = cb4[o];
#pragma unroll
    for (int ci = 0; ci < 16; ci++) s += v[ci]*cw4[o*16+ci];
    t4[o*HW+p] = s;
  }
}

__global__ __launch_bounds__(256) void k_instats1(const float* __restrict__ t4,
                                                  float* __restrict__ part) {
  int c = blockIdx.x >> 4, seg = blockIdx.x & 15;   // 512 blocks
  const float4* src = (const float4*)(t4 + c*HW + seg*4096);
  float s = 0.f, ss = 0.f;
  for (int i = threadIdx.x; i < 1024; i += 256) {
    float4 v = src[i];
    s  += v.x + v.y + v.z + v.w;
    ss += v.x*v.x + v.y*v.y + v.z*v.z + v.w*v.w;
  }
#pragma unroll
  for (int off = 32; off > 0; off >>= 1) {
    s  += __shfl_down(s, off, 64);
    ss += __shfl_down(ss, off, 64);
  }
  __shared__ float sh[8];
  int wid = threadIdx.x >> 6;
  if ((threadIdx.x & 63) == 0) { sh[wid] = s; sh[4+wid] = ss; }
  __syncthreads();
  if (threadIdx.x == 0) {
    part[blockIdx.x]       = sh[0]+sh[1]+sh[2]+sh[3];
    part[512 + blockIdx.x] = sh[4]+sh[5]+sh[6]+sh[7];
  }
}

// ---------------- MFMA attention, S^T formulation (no P LDS round-trip) ----------------
__global__ __launch_bounds__(256) void k_attn(
    const float* __restrict__ qA, const float* __restrict__ kvA, float* __restrict__ aoA,
    const float* __restrict__ qB, const float* __restrict__ kvB, float* __restrict__ aoB,
    const float* __restrict__ biasT) {
  __shared__ __align__(16) unsigned short Qs[256*16];   // [q][d]
  __shared__ __align__(16) unsigned short Ks[576*16];   // [key][d]
  __shared__ __align__(16) unsigned short Vt[16*KPAD];  // [d][key-permuted]

  const float* q  = blockIdx.y ? qB  : qA;
  const float* kv = blockIdx.y ? kvB : kvA;
  float* ao       = blockIdx.y ? aoB : aoA;

  int wi = blockIdx.x >> 1, hd = blockIdx.x & 1;
  int wy = wi >> 4, wx = wi & 15;
  int t = threadIdx.x;
  int by = wy*16 - 4, bx = wx*16 - 4;
  int kbase = hd*16*HW, vbase = (32 + hd*16)*HW;

  {
    int qy = wy*16 + (t >> 4), qx = wx*16 + (t & 15);
    int p = qy*256 + qx;
    unsigned short tmp[16];
#pragma unroll
    for (int i = 0; i < 16; i++) tmp[i] = f2b(q[(hd*16+i)*HW + p] * 0.25f);
    *(uint4*)&Qs[t*16]     = *(uint4*)&tmp[0];
    *(uint4*)&Qs[t*16 + 8] = *(uint4*)&tmp[8];
  }
  for (int e = t; e < 576; e += 256) {
    int dy = e / 24, dx = e - dy*24;
    int yy = by + dy, xx = bx + dx;
    bool ok = ((unsigned)yy < 256u) && ((unsigned)xx < 256u);
    int pp = yy*256 + xx;
    // V permuted within each 32-key block: ppos matches PV A-slot order
    int off = e & 31;
    int ppos = ((off & 12) << 1) + ((off >> 4) << 2) + (off & 3);
    int vcol = (e & ~31) + ppos;
    unsigned short tk[16];
#pragma unroll
    for (int i = 0; i < 16; i++) {
      float kvl = ok ? kv[kbase + i*HW + pp] : 0.f;
      float vvl = ok ? kv[vbase + i*HW + pp] : 0.f;
      tk[i] = f2b(kvl);
      Vt[i*KPAD + vcol] = f2b(vvl);
    }
    *(uint4*)&Ks[e*16]     = *(uint4*)&tk[0];
    *(uint4*)&Ks[e*16 + 8] = *(uint4*)&tk[8];
  }
  __syncthreads();

  int wave = t >> 6, lane = t & 63;
  int quad = lane >> 4, l16 = lane & 15;
  const bf8 zero8 = {0,0,0,0,0,0,0,0};

#pragma unroll 1
  for (int pp2 = 0; pp2 < 2; pp2++) {
    int qta = wave*4 + pp2*2, qtb = qta + 1;   // two q-tiles in flight (ILP)
    bf8 qfa = zero8, qfb = zero8;
    if (quad < 2) {
      qfa = *(const bf8*)&Qs[(qta*16 + l16)*16 + quad*8];
      qfb = *(const bf8*)&Qs[(qtb*16 + l16)*16 + quad*8];
    }
    f4 oa = {0.f,0.f,0.f,0.f}, ob = {0.f,0.f,0.f,0.f};
    float la = 0.f, lb = 0.f;
    const float* bba = biasT + (hd*16 + qta)*9216 + quad*64 + l16*4;
    const float* bbb = biasT + (hd*16 + qtb)*9216 + quad*64 + l16*4;
    f4 ba0 = *(const f4*)&bba[0];
    f4 ba1 = *(const f4*)&bba[256];
    f4 bb0 = *(const f4*)&bbb[0];
    f4 bb1 = *(const f4*)&bbb[256];

#pragma unroll 2
    for (int kt2 = 0; kt2 < 18; kt2++) {
      int k0 = kt2 * 32;
      f4 na0 = *(const f4*)&bba[(k0+32)*16];
      f4 na1 = *(const f4*)&bba[(k0+48)*16];
      f4 nb0 = *(const f4*)&bbb[(k0+32)*16];
      f4 nb1 = *(const f4*)&bbb[(k0+48)*16];
      bf8 kf0 = zero8, kf1 = zero8;
      if (quad < 2) {
        kf0 = *(const bf8*)&Ks[(k0 + l16)*16 + quad*8];
        kf1 = *(const bf8*)&Ks[(k0 + 16 + l16)*16 + quad*8];
      }
      // S^T = K·Q^T + bias^T : lane holds (key=k0(+16)+quad*4+r, q=l16)
      f4 sa0 = __builtin_amdgcn_mfma_f32_16x16x32_bf16(kf0, qfa, ba0, 0, 0, 0);
      f4 sa1 = __builtin_amdgcn_mfma_f32_16x16x32_bf16(kf1, qfa, ba1, 0, 0, 0);
      f4 sb0 = __builtin_amdgcn_mfma_f32_16x16x32_bf16(kf0, qfb, bb0, 0, 0, 0);
      f4 sb1 = __builtin_amdgcn_mfma_f32_16x16x32_bf16(kf1, qfb, bb1, 0, 0, 0);
      float pa0[4], pa1[4], pb0[4], pb1[4];
#pragma unroll
      for (int r = 0; r < 4; r++) {
        pa0[r] = __expf(sa0[r]); pa1[r] = __expf(sa1[r]);
        pb0[r] = __expf(sb0[r]); pb1[r] = __expf(sb1[r]);
        la += pa0[r] + pa1[r];
        lb += pb0[r] + pb1[r];
      }
      // P^T C-layout == PV A-layout: pack in registers (bf16 truncation)
      union { unsigned int u[4]; bf8 v; } Pa, Pb;
      Pa.u[0] = pk2(pa0[0], pa0[1]); Pa.u[1] = pk2(pa0[2], pa0[3]);
      Pa.u[2] = pk2(pa1[0], pa1[1]); Pa.u[3] = pk2(pa1[2], pa1[3]);
      Pb.u[0] = pk2(pb0[0], pb0[1]); Pb.u[1] = pk2(pb0[2], pb0[3]);
      Pb.u[2] = pk2(pb1[0], pb1[1]); Pb.u[3] = pk2(pb1[2], pb1[3]);
      bf8 vf = *(const bf8*)&Vt[l16*KPAD + k0 + quad*8];   // permuted slots match A
      oa = __builtin_amdgcn_mfma_f32_16x16x32_bf16(Pa.v, vf, oa, 0, 0, 0);
      ob = __builtin_amdgcn_mfma_f32_16x16x32_bf16(Pb.v, vf, ob, 0, 0, 0);
      ba0 = na0; ba1 = na1; bb0 = nb0; bb1 = nb1;
    }
    la += __shfl_xor(la, 16, 64); la += __shfl_xor(la, 32, 64);
    lb += __shfl_xor(lb, 16, 64); lb += __shfl_xor(lb, 32, 64);
#pragma unroll
    for (int r = 0; r < 4; r++) {
      float lva = __shfl(la, quad*4 + r, 64);
      float lvb = __shfl(lb, quad*4 + r, 64);
      int qwa = qta*16 + quad*4 + r;
      int qwb = qtb*16 + quad*4 + r;
      ao[(hd*16 + l16)*HW + (wy*16 + (qwa >> 4))*256 + wx*16 + (qwa & 15)] = oa[r] / lva;
      ao[(hd*16 + l16)*HW + (wy*16 + (qwb >> 4))*256 + wx*16 + (qwb & 15)] = ob[r] / lvb;
    }
  }
}

// ---------------- proj+shortcut+LN+MLP, ONE ocab per block (R5-proven, no spill) ----------------
__global__ __launch_bounds__(256) void k_projmlp(
    const float* __restrict__ ao1, const float* __restrict__ ao2,
    const float* __restrict__ x, const float* __restrict__ t4,
    const float* __restrict__ part,
    const float* __restrict__ ig, const float* __restrict__ ib,
    const float* __restrict__ wp, const float* __restrict__ bp,
    const float* __restrict__ n2g, const float* __restrict__ n2b,
    const float* __restrict__ mw1, const float* __restrict__ mb1,
    const float* __restrict__ mw2, const float* __restrict__ mb2,
    float* __restrict__ o1, float* __restrict__ o2, int obase) {
  int oc = blockIdx.y + obase;
  const float* ao = oc ? ao2 : ao1;
  float* dst      = oc ? o2  : o1;
  __shared__ __align__(16) float wps[1024];
  __shared__ __align__(16) float w1s[2048];
  __shared__ __align__(16) float w2s[2048];
  __shared__ float bps[32], b1s[64], b2s[32], gs[32], bs[32], as[32], bbs[32];
  int t = threadIdx.x;
  for (int i = t; i < 1024; i += 256) wps[i] = wp[i];
  for (int i = t; i < 2048; i += 256) { w1s[i] = mw1[i]; w2s[i] = mw2[i]; }
  if (t < 64) b1s[t] = mb1[t];
  if (t < 32) {
    bps[t] = bp[t]; b2s[t] = mb2[t]; gs[t] = n2g[t]; bs[t] = n2b[t];
    float s = 0.f, ss = 0.f;
#pragma unroll
    for (int k = 0; k < 16; k++) { s += part[t*16+k]; ss += part[512 + t*16+k]; }
    float m = s * (1.f/65536.f);
    float var = ss * (1.f/65536.f) - m*m;
    float a = rsqrtf(var + 1e-5f) * ig[t];
    as[t] = a; bbs[t] = ib[t] - m*a;
  }
  __syncthreads();
  int p = blockIdx.x*256 + t;
  float acc[32];
#pragma unroll
  for (int j = 0; j < 32; j++) acc[j] = bps[j];
#pragma unroll
  for (int c = 0; c < 32; c++) {
    float vc = ao[c*HW+p];
    const float4* w4 = (const float4*)&wps[c*32];
#pragma unroll
    for (int j4 = 0; j4 < 8; j4++) {
      float4 w = w4[j4];
      acc[j4*4+0] += vc*w.x; acc[j4*4+1] += vc*w.y;
      acc[j4*4+2] += vc*w.z; acc[j4*4+3] += vc*w.w;
    }
  }
  if (oc == 0) {
#pragma unroll
    for (int j = 0; j < 32; j++) acc[j] += x[j*HW+p];
  } else {
#pragma unroll
    for (int j = 0; j < 32; j++) acc[j] += t4[j*HW+p]*as[j] + bbs[j];
  }
  float s = 0.f;
#pragma unroll
  for (int j = 0; j < 32; j++) s += acc[j];
  float m = s * 0.03125f;
  float ss = 0.f;
#pragma unroll
  for (int j = 0; j < 32; j++) { float d = acc[j]-m; ss += d*d; }
  float rs = rsqrtf(ss*0.03125f + 1e-5f);
  float r[32];
#pragma unroll
  for (int j = 0; j < 32; j++) r[j] = b2s[j];
#pragma unroll 1
  for (int half = 0; half < 2; half++) {
    float h[32];
#pragma unroll
    for (int k = 0; k < 32; k++) h[k] = b1s[half*32 + k];
#pragma unroll
    for (int c = 0; c < 32; c++) {
      float ln = (acc[c] - m) * rs * gs[c] + bs[c];
      const float4* w4 = (const float4*)&w1s[c*64 + half*32];
#pragma unroll
      for (int k4 = 0; k4 < 8; k4++) {
        float4 w = w4[k4];
        h[k4*4+0] += ln*w.x; h[k4*4+1] += ln*w.y; h[k4*4+2] += ln*w.z; h[k4*4+3] += ln*w.w;
      }
    }
#pragma unroll
    for (int k = 0; k < 32; k++) {
      float xx = h[k];
      float u = 0.7978845608f * (xx + 0.044715f*xx*xx*xx);
      float th = 1.f - 2.f/(1.f + __expf(2.f*u));
      h[k] = 0.5f * xx * (1.f + th);
    }
#pragma unroll
    for (int k = 0; k < 32; k++) {
      float hk = h[k];
      const float4* w4 = (const float4*)&w2s[(half*32 + k)*32];
#pragma unroll
      for (int j4 = 0; j4 < 8; j4++) {
        float4 w = w4[j4];
        r[j4*4+0] += hk*w.x; r[j4*4+1] += hk*w.y; r[j4*4+2] += hk*w.z; r[j4*4+3] += hk*w.w;
      }
    }
  }
#pragma unroll
  for (int j = 0; j < 32; j++) dst[j*HW + p] = acc[j] + r[j];
}

// ---------------- final: out = o1 + o2 + x (o1 aliases out) ----------------
__global__ __launch_bounds__(256) void k_final(
    const float* o1, const float* __restrict__ o2,
    const float* __restrict__ x, float* out) {
  int i = blockIdx.x*256 + threadIdx.x;
  float4 a = ((const float4*)o1)[i];
  float4 b = ((const float4*)o2)[i];
  float4 c = ((const float4*)x)[i];
  float4 r;
  r.x = a.x + b.x + c.x; r.y = a.y + b.y + c.y;
  r.z = a.z + b.z + c.z; r.w = a.w + b.w + c.w;
  ((float4*)out)[i] = r;
}

extern "C" void kernel_launch(void* const* d_in, const int* in_sizes, int n_in,
                              void* d_out, int out_size, void* d_ws, size_t ws_size,
                              hipStream_t stream) {
  const float* x    = (const float*)d_in[0];
  const float* depth= (const float*)d_in[1];
  const int*   rpi  = (const int*)d_in[2];
  const float* cw1  = (const float*)d_in[3],  *cb1 = (const float*)d_in[4];
  const float* cw2  = (const float*)d_in[5],  *cb2 = (const float*)d_in[6];
  const float* cw3  = (const float*)d_in[7],  *cb3 = (const float*)d_in[8];
  const float* cw4  = (const float*)d_in[9],  *cb4 = (const float*)d_in[10];
  const float* in_g = (const float*)d_in[11], *in_b = (const float*)d_in[12];
  const float* n1g  = (const float*)d_in[13], *n1b = (const float*)d_in[14];
  const float* wq   = (const float*)d_in[15], *bq  = (const float*)d_in[16];
  const float* wkv  = (const float*)d_in[17], *bkv = (const float*)d_in[18];
  const float* rpb  = (const float*)d_in[19];
  const float* wp   = (const float*)d_in[20], *bp  = (const float*)d_in[21];
  const float* n2g  = (const float*)d_in[22], *n2b = (const float*)d_in[23];
  const float* mw1  = (const float*)d_in[24], *mb1 = (const float*)d_in[25];
  const float* mw2  = (const float*)d_in[26], *mb2 = (const float*)d_in[27];

  float* W   = (float*)d_ws;
  float* o1  = (float*)d_out;

  bool big = ws_size >= (size_t)85100000;   // merged path needs ~85.07 MB

  if (big) {
    float* t4    = W;                    // 2M floats
    float* q1    = W + 2097152;
    float* q2    = W + 4194304;          // t3 aliases first 1M
    float* kv1   = W + 6291456;          // 4M
    float* kv2   = W + 10485760;         // 4M
    float* ao1   = W + 14680064;         // t2 aliases first 1M
    float* ao2   = W + 16777216;
    float* o2    = W + 18874368;
    float* biasT = W + 20971520;         // 294912
    float* part  = W + 21266432;         // 1024
    float* t2 = ao1, *t3 = q2;

    k_misc   <<<dim3(1152,5), 256, 0, stream>>>(depth, cw1, cb1, cw2, cb2, t2,
                                                rpi, rpb, biasT,
                                                x, t4, part, in_g, in_b, n1g, n1b,
                                                wq, bq, wkv, bkv, q1, kv1, q2, kv2);
    k_conv3  <<<dim3(256,4), 256, 0, stream>>>(t2, cw3, cb3, t3);
    k_conv4  <<<256, 256, 0, stream>>>(t3, cw4, cb4, t4);
    k_instats1<<<512, 256, 0, stream>>>(t4, part);
    k_lnmm3  <<<dim3(256,3), 256, 0, stream>>>(x, t4, part, in_g, in_b, n1g, n1b,
                                               wq, bq, wkv, bkv, q1, kv1, q2, kv2, 1);
    k_attn   <<<dim3(512,2), 256, 0, stream>>>(q1, kv1, ao1, q2, kv2, ao2, biasT);
    k_projmlp<<<dim3(256,2), 256, 0, stream>>>(ao1, ao2, x, t4, part, in_g, in_b,
                                               wp, bp, n2g, n2b, mw1, mb1, mw2, mb2,
                                               o1, o2, 0);
    k_final  <<<2048, 256, 0, stream>>>(o1, o2, x, o1);
  } else {
    // serial fallback, ~51.5 MB
    float* t4    = W;
    float* q1    = W + 2097152;
    float* kv1   = W + 4194304;          // 4M
    float* ao1   = W + 8388608;          // t2 aliases first 1M
    float* o2    = W + 10485760;         // t3 aliases first 1M
    float* biasT = W + 12582912;
    float* part  = W + 12877824;
    float* t2 = ao1, *t3 = o2;

    k_misc   <<<dim3(1152,2), 256, 0, stream>>>(depth, cw1, cb1, cw2, cb2, t2,
                                                rpi, rpb, biasT,
                                                x, t4, part, in_g, in_b, n1g, n1b,
                                                wq, bq, wkv, bkv, q1, kv1, q1, kv1);
    k_conv3  <<<dim3(256,4), 256, 0, stream>>>(t2, cw3, cb3, t3);
    k_conv4  <<<256, 256, 0, stream>>>(t3, cw4, cb4, t4);
    k_instats1<<<512, 256, 0, stream>>>(t4, part);
    k_lnmm3  <<<dim3(256,3), 256, 0, stream>>>(x, t4, part, in_g, in_b, n1g, n1b,
                                               wq, bq, wkv, bkv, q1, kv1, q1, kv1, 0);
    k_attn   <<<dim3(512,1), 256, 0, stream>>>(q1, kv1, ao1, q1, kv1, ao1, biasT);
    k_projmlp<<<dim3(256,1), 256, 0, stream>>>(ao1, ao1, x, t4, part, in_g, in_b,
                                               wp, bp, n2g, n2b, mw1, mb1, mw2, mb2,
                                               o1, o2, 0);
    k_lnmm3  <<<dim3(256,3), 256, 0, stream>>>(x, t4, part, in_g, in_b, n1g, n1b,
                                               wq, bq, wkv, bkv, q1, kv1, q1, kv1, 3);
    k_attn   <<<dim3(512,1), 256, 0, stream>>>(q1, kv1, ao1, q1, kv1, ao1, biasT);
    k_projmlp<<<dim3(256,1), 256, 0, stream>>>(ao1, ao1, x, t4, part, in_g, in_b,
                                               wp, bp, n2g, n2b, mw1, mb1, mw2, mb2,
                                               o1, o2, 1);
    k_final  <<<2048, 256, 0, stream>>>(o1, o2, x, o1);
  }
}

// Round 8
// 279.664 us; speedup vs baseline: 2.4242x; 1.0601x over previous
//
#include <hip/hip_runtime.h>
#include <hip/hip_bf16.h>

#define HW 65536
#define KPAD 584   // Vt row stride (bf16): 1168B rows, 16B-aligned

typedef __attribute__((ext_vector_type(8))) short bf8;
typedef __attribute__((ext_vector_type(4))) float f4;

__device__ __forceinline__ unsigned short f2b(float x) {   // RNE float->bf16
  unsigned int u = __float_as_uint(x);
  unsigned int r = (u + 0x7fff + ((u >> 16) & 1)) >> 16;
  return (unsigned short)r;
}
__device__ __forceinline__ unsigned int pk2(float lo, float hi) {  // trunc pack 2xbf16
  return (__float_as_uint(hi) & 0xffff0000u) | (__float_as_uint(lo) >> 16);
}
__device__ __forceinline__ float ex2(float x) { return __builtin_amdgcn_exp2f(x); }

// ================= device bodies =================
__device__ __forceinline__ void stem_front_body(
    int bx, int t, const float* __restrict__ depth,
    const float* __restrict__ cw1, const float* __restrict__ cb1,
    const float* __restrict__ cw2, const float* __restrict__ cb2,
    float* __restrict__ t2) {
  int p = bx * 256 + t;
  int y = p >> 8, x = p & 255;
  float in9[9];
#pragma unroll
  for (int ky = 0; ky < 3; ky++)
#pragma unroll
    for (int kx = 0; kx < 3; kx++) {
      int yy = y + ky - 1, xx = x + kx - 1;
      bool ok = ((unsigned)yy < 256u) && ((unsigned)xx < 256u);
      in9[ky*3+kx] = ok ? depth[yy*256+xx] : 0.f;
    }
  float t1[8];
#pragma unroll
  for (int o = 0; o < 8; o++) {
    float s = cb1[o];
#pragma unroll
    for (int i = 0; i < 9; i++) s += in9[i] * cw1[o*9+i];
    t1[o] = fmaxf(s, 0.f);
  }
#pragma unroll
  for (int o = 0; o < 16; o++) {
    float s = cb2[o];
#pragma unroll
    for (int ci = 0; ci < 8; ci++) s += t1[ci] * cw2[o*8+ci];
    t2[o*HW + p] = fmaxf(s, 0.f);
  }
}

// bias layout per (hd,qt): [kb=key/4][q16][r=key&3]; pre-scaled by 1/ln2 with -8 shift
__device__ __forceinline__ void bias_body(
    int bx, int t, const int* __restrict__ rpi,
    const float* __restrict__ rpb, float* __restrict__ biasT) {
  int idx = bx*256 + t;        // 1152*256 = 294912 exact
  int hd = idx / 147456;
  int rem = idx - hd*147456;
  int qt = rem / 9216;
  int r2 = rem - qt*9216;
  int kb = r2 >> 6;
  int q16 = (r2 >> 2) & 15;
  int r = r2 & 3;
  int key = kb*4 + r;
  int qq = qt*16 + q16;
  biasT[idx] = (rpb[rpi[qq*576 + key]*2 + hd] - 8.0f) * 1.44269504f;
}

// 16-output LN(+IN) matmul slab.
// roles: 0/1: q1 = LN(x)@wq cols 0/16        2..5: kv2 = LN(x)@wkv cols 16c
//        6/7: q2 = LN(IN(t4))@wq cols 0/16   8..11: kv1 = LN(IN(t4))@wkv cols 16c
__device__ __forceinline__ void lnmm16_body(
    int role, int bx, int t,
    float* ws, float* gs, float* bs, float* b2s, float* as, float* bbs,
    const float* __restrict__ x, const float* __restrict__ t4,
    const float* __restrict__ part,
    const float* __restrict__ ig, const float* __restrict__ ib,
    const float* __restrict__ n1g, const float* __restrict__ n1b,
    const float* __restrict__ wq, const float* __restrict__ bq,
    const float* __restrict__ wkv, const float* __restrict__ bkv,
    float* q1, float* kv1, float* q2, float* kv2) {
  const float *src, *wm, *bo; float* dst;
  int wstride, wcol; bool ain;
  if (role < 6) { src = x;  ain = false; } else { src = t4; ain = true; }
  switch (role) {
    default:
    case 0:  wm=wq;  wstride=32; wcol=0;  bo=bq;  dst=q1;               break;
    case 1:  wm=wq;  wstride=32; wcol=16; bo=bq;  dst=q1+16*HW;         break;
    case 2: case 3: case 4: case 5:
             wm=wkv; wstride=64; wcol=16*(role-2); bo=bkv; dst=kv2+16*(role-2)*HW; break;
    case 6:  wm=wq;  wstride=32; wcol=0;  bo=bq;  dst=q2;               break;
    case 7:  wm=wq;  wstride=32; wcol=16; bo=bq;  dst=q2+16*HW;         break;
    case 8: case 9: case 10: case 11:
             wm=wkv; wstride=64; wcol=16*(role-8); bo=bkv; dst=kv1+16*(role-8)*HW; break;
  }
  for (int i = t; i < 512; i += 256) ws[i] = wm[(i>>4)*wstride + wcol + (i&15)];
  if (t < 16) b2s[t] = bo[wcol + t];
  if (t < 32) {
    gs[t] = n1g[t]; bs[t] = n1b[t];
    if (ain) {
      float s = 0.f, ss = 0.f;
#pragma unroll
      for (int k = 0; k < 16; k++) { s += part[t*16+k]; ss += part[512 + t*16+k]; }
      float m = s * (1.f/65536.f);
      float var = ss * (1.f/65536.f) - m*m;
      float a = rsqrtf(var + 1e-5f) * ig[t];
      as[t] = a; bbs[t] = ib[t] - m*a;
    }
  }
  __syncthreads();
  int p = bx*256 + t;
  float v[32]; float s = 0.f;
  if (ain) {
#pragma unroll
    for (int c = 0; c < 32; c++) { v[c] = src[c*HW+p]*as[c] + bbs[c]; s += v[c]; }
  } else {
#pragma unroll
    for (int c = 0; c < 32; c++) { v[c] = src[c*HW+p]; s += v[c]; }
  }
  float m = s * 0.03125f;
  float ss = 0.f;
#pragma unroll
  for (int c = 0; c < 32; c++) { float d = v[c]-m; ss += d*d; }
  float rs = rsqrtf(ss*0.03125f + 1e-5f);
  float acc[16];
#pragma unroll
  for (int j = 0; j < 16; j++) acc[j] = b2s[j];
#pragma unroll
  for (int c = 0; c < 32; c++) {
    float ln = (v[c]-m)*rs*gs[c] + bs[c];
    const float4* w4 = (const float4*)&ws[c*16];
#pragma unroll
    for (int j4 = 0; j4 < 4; j4++) {
      float4 w = w4[j4];
      acc[j4*4+0] += ln*w.x; acc[j4*4+1] += ln*w.y;
      acc[j4*4+2] += ln*w.z; acc[j4*4+3] += ln*w.w;
    }
  }
#pragma unroll
  for (int j = 0; j < 16; j++) dst[j*HW+p] = acc[j];
}

// ================= kernels =================
// mega-launch: y=0 stem_front (256) | y=1 bias (1152) | y=2..(2+nln-1): lnmm16 roles 0..nln-1
__global__ __launch_bounds__(256) void k_misc(
    const float* __restrict__ depth,
    const float* __restrict__ cw1, const float* __restrict__ cb1,
    const float* __restrict__ cw2, const float* __restrict__ cb2,
    float* __restrict__ t2,
    const int* __restrict__ rpi, const float* __restrict__ rpb, float* __restrict__ biasT,
    const float* __restrict__ x, const float* __restrict__ t4, const float* __restrict__ part,
    const float* __restrict__ ig, const float* __restrict__ ib,
    const float* __restrict__ n1g, const float* __restrict__ n1b,
    const float* __restrict__ wq, const float* __restrict__ bq,
    const float* __restrict__ wkv, const float* __restrict__ bkv,
    float* q1, float* kv1, float* q2, float* kv2) {
  __shared__ __align__(16) float ws[512];
  __shared__ float gs[32], bs[32], b2s[16], as[32], bbs[32];
  int role = blockIdx.y, t = threadIdx.x, bx = blockIdx.x;
  if (role == 0) { if (bx < 256) stem_front_body(bx, t, depth, cw1, cb1, cw2, cb2, t2); return; }
  if (role == 1) { bias_body(bx, t, rpi, rpb, biasT); return; }
  if (bx >= 256) return;
  lnmm16_body(role - 2, bx, t, ws, gs, bs, b2s, as, bbs,
              x, t4, part, ig, ib, n1g, n1b, wq, bq, wkv, bkv, q1, kv1, q2, kv2);
}

__global__ __launch_bounds__(256) void k_lnmmB(
    const float* __restrict__ x, const float* __restrict__ t4, const float* __restrict__ part,
    const float* __restrict__ ig, const float* __restrict__ ib,
    const float* __restrict__ n1g, const float* __restrict__ n1b,
    const float* __restrict__ wq, const float* __restrict__ bq,
    const float* __restrict__ wkv, const float* __restrict__ bkv,
    float* q1, float* kv1, float* q2, float* kv2, int ybase) {
  __shared__ __align__(16) float ws[512];
  __shared__ float gs[32], bs[32], b2s[16], as[32], bbs[32];
  lnmm16_body(ybase + blockIdx.y, blockIdx.x, threadIdx.x, ws, gs, bs, b2s, as, bbs,
              x, t4, part, ig, ib, n1g, n1b, wq, bq, wkv, bkv, q1, kv1, q2, kv2);
}

__global__ __launch_bounds__(256) void k_conv3(
    const float* __restrict__ t2, const float* __restrict__ cw3,
    const float* __restrict__ cb3, float* __restrict__ t3) {
  int t = threadIdx.x;
  int p = blockIdx.x*256 + t;
  int og = blockIdx.y;
  int y = p >> 8, x = p & 255;
  float acc[4];
#pragma unroll
  for (int o = 0; o < 4; o++) acc[o] = cb3[og*4+o];
#pragma unroll 1
  for (int tap = 0; tap < 9; tap++) {
    int ky = tap/3 - 1, kx = tap - (tap/3)*3 - 1;
    int yy = y+ky, xx = x+kx;
    bool ok = ((unsigned)yy < 256u) && ((unsigned)xx < 256u);
    int pp = yy*256+xx;
#pragma unroll
    for (int ci = 0; ci < 16; ci++) {
      float v = ok ? t2[ci*HW+pp] : 0.f;
#pragma unroll
      for (int o = 0; o < 4; o++)
        acc[o] += v * cw3[(og*4+o)*144 + ci*9 + tap];   // uniform -> s_load
    }
  }
#pragma unroll
  for (int o = 0; o < 4; o++) t3[(og*4+o)*HW+p] = fmaxf(acc[o], 0.f);
}

// conv4 split over y: 8 outputs per block -> 1024 blocks (4 waves/SIMD)
__global__ __launch_bounds__(256) void k_conv4(
    const float* __restrict__ t3, const float* __restrict__ cw4,
    const float* __restrict__ cb4, float* __restrict__ t4) {
  int t = threadIdx.x;
  int p = blockIdx.x*256 + t;
  int og = blockIdx.y;           // 8 outputs per group
  float v[16];
#pragma unroll
  for (int ci = 0; ci < 16; ci++) v[ci] = t3[ci*HW+p];
#pragma unroll
  for (int o = 0; o < 8; o++) {
    int oo = og*8 + o;
    float s = cb4[oo];
#pragma unroll
    for (int ci = 0; ci < 16; ci++) s += v[ci]*cw4[oo*16+ci];
    t4[oo*HW+p] = s;
  }
}

__global__ __launch_bounds__(256) void k_instats1(const float* __restrict__ t4,
                                                  float* __restrict__ part) {
  int c = blockIdx.x >> 4, seg = blockIdx.x & 15;   // 512 blocks
  const float4* src = (const float4*)(t4 + c*HW + seg*4096);
  float s = 0.f, ss = 0.f;
  for (int i = threadIdx.x; i < 1024; i += 256) {
    float4 v = src[i];
    s  += v.x + v.y + v.z + v.w;
    ss += v.x*v.x + v.y*v.y + v.z*v.z + v.w*v.w;
  }
#pragma unroll
  for (int off = 32; off > 0; off >>= 1) {
    s  += __shfl_down(s, off, 64);
    ss += __shfl_down(ss, off, 64);
  }
  __shared__ float sh[8];
  int wid = threadIdx.x >> 6;
  if ((threadIdx.x & 63) == 0) { sh[wid] = s; sh[4+wid] = ss; }
  __syncthreads();
  if (threadIdx.x == 0) {
    part[blockIdx.x]       = sh[0]+sh[1]+sh[2]+sh[3];
    part[512 + blockIdx.x] = sh[4]+sh[5]+sh[6]+sh[7];
  }
}

// ---------------- MFMA attention: S^T form, 4 q-tiles in flight, XCD-swizzled ----------------
__global__ __launch_bounds__(256, 3) void k_attn(
    const float* __restrict__ qA, const float* __restrict__ kvA, float* __restrict__ aoA,
    const float* __restrict__ qB, const float* __restrict__ kvB, float* __restrict__ aoB,
    const float* __restrict__ biasT) {
  __shared__ __align__(16) unsigned short Qs[256*16];   // [q][d]
  __shared__ __align__(16) unsigned short Ks[576*16];   // [key][d]
  __shared__ __align__(16) unsigned short Vt[16*KPAD];  // [d][key-permuted]

  const float* q  = blockIdx.y ? qB  : qA;
  const float* kv = blockIdx.y ? kvB : kvA;
  float* ao       = blockIdx.y ? aoB : aoA;

  // XCD swizzle: give each XCD a contiguous stripe of windows for kv-overlap L2 reuse
  int id = blockIdx.x;                       // 0..511
  int lin = ((id & 7) << 6) | (id >> 3);
  int wi = lin >> 1, hd = lin & 1;
  int wy = wi >> 4, wx = wi & 15;
  int t = threadIdx.x;
  int by = wy*16 - 4, bx = wx*16 - 4;
  int kbase = hd*16*HW, vbase = (32 + hd*16)*HW;

  {
    int qy = wy*16 + (t >> 4), qx = wx*16 + (t & 15);
    int p = qy*256 + qx;
    unsigned short tmp[16];
#pragma unroll
    for (int i = 0; i < 16; i++) tmp[i] = f2b(q[(hd*16+i)*HW + p] * 0.360673503f); // 0.25/ln2
    *(uint4*)&Qs[t*16]     = *(uint4*)&tmp[0];
    *(uint4*)&Qs[t*16 + 8] = *(uint4*)&tmp[8];
  }
  for (int e = t; e < 576; e += 256) {
    int dy = e / 24, dx = e - dy*24;
    int yy = by + dy, xx = bx + dx;
    bool ok = ((unsigned)yy < 256u) && ((unsigned)xx < 256u);
    int pp = yy*256 + xx;
    // V permuted within each 32-key block: slot = q4*8 + half*4 + r (PV A-slot order)
    int off = e & 31;
    int ppos = ((off & 12) << 1) + ((off >> 4) << 2) + (off & 3);
    int vcol = (e & ~31) + ppos;
    unsigned short tk[16];
#pragma unroll
    for (int i = 0; i < 16; i++) {
      float kvl = ok ? kv[kbase + i*HW + pp] : 0.f;
      float vvl = ok ? kv[vbase + i*HW + pp] : 0.f;
      tk[i] = f2b(kvl);
      Vt[i*KPAD + vcol] = f2b(vvl);
    }
    *(uint4*)&Ks[e*16]     = *(uint4*)&tk[0];
    *(uint4*)&Ks[e*16 + 8] = *(uint4*)&tk[8];
  }
  __syncthreads();

  int wave = t >> 6, lane = t & 63;
  int quad = lane >> 4, l16 = lane & 15;
  const bf8 zero8 = {0,0,0,0,0,0,0,0};

  bf8 qf[4];
  f4 oacc[4];
  float lr[4];
  const float* bb[4];
#pragma unroll
  for (int qi = 0; qi < 4; qi++) {
    int qt = wave*4 + qi;
    qf[qi] = zero8;
    if (quad < 2) qf[qi] = *(const bf8*)&Qs[(qt*16 + l16)*16 + quad*8];
    oacc[qi] = (f4){0.f,0.f,0.f,0.f};
    lr[qi] = 0.f;
    bb[qi] = biasT + (hd*16 + qt)*9216 + quad*64 + l16*4;
  }

#pragma unroll 2
  for (int kt2 = 0; kt2 < 18; kt2++) {
    int k0 = kt2 * 32;
    bf8 kf0 = zero8, kf1 = zero8;
    if (quad < 2) {
      kf0 = *(const bf8*)&Ks[(k0 + l16)*16 + quad*8];
      kf1 = *(const bf8*)&Ks[(k0 + 16 + l16)*16 + quad*8];
    }
    bf8 vf = *(const bf8*)&Vt[l16*KPAD + k0 + quad*8];
#pragma unroll
    for (int qi = 0; qi < 4; qi++) {
      f4 b0 = *(const f4*)&bb[qi][k0*16];
      f4 b1 = *(const f4*)&bb[qi][(k0+16)*16];
      f4 s0 = __builtin_amdgcn_mfma_f32_16x16x32_bf16(kf0, qf[qi], b0, 0, 0, 0);
      f4 s1 = __builtin_amdgcn_mfma_f32_16x16x32_bf16(kf1, qf[qi], b1, 0, 0, 0);
      float p0[4], p1[4];
#pragma unroll
      for (int r = 0; r < 4; r++) {
        p0[r] = ex2(s0[r]);
        p1[r] = ex2(s1[r]);
        lr[qi] += p0[r] + p1[r];
      }
      union { unsigned int u[4]; bf8 v; } P;
      P.u[0] = pk2(p0[0], p0[1]); P.u[1] = pk2(p0[2], p0[3]);
      P.u[2] = pk2(p1[0], p1[1]); P.u[3] = pk2(p1[2], p1[3]);
      oacc[qi] = __builtin_amdgcn_mfma_f32_16x16x32_bf16(P.v, vf, oacc[qi], 0, 0, 0);
    }
  }
#pragma unroll
  for (int qi = 0; qi < 4; qi++) {
    lr[qi] += __shfl_xor(lr[qi], 16, 64);
    lr[qi] += __shfl_xor(lr[qi], 32, 64);
  }
#pragma unroll
  for (int qi = 0; qi < 4; qi++) {
    int qt = wave*4 + qi;
#pragma unroll
    for (int r = 0; r < 4; r++) {
      float lv = __shfl(lr[qi], quad*4 + r, 64);
      int qw = qt*16 + quad*4 + r;
      ao[(hd*16 + l16)*HW + (wy*16 + (qw >> 4))*256 + wx*16 + (qw & 15)] = oacc[qi][r] / lv;
    }
  }
}

// ---------------- proj+shortcut+LN+MLP, ONE ocab per block (proven, no spill) ----------------
__global__ __launch_bounds__(256) void k_projmlp(
    const float* __restrict__ ao1, const float* __restrict__ ao2,
    const float* __restrict__ x, const float* __restrict__ t4,
    const float* __restrict__ part,
    const float* __restrict__ ig, const float* __restrict__ ib,
    const float* __restrict__ wp, const float* __restrict__ bp,
    const float* __restrict__ n2g, const float* __restrict__ n2b,
    const float* __restrict__ mw1, const float* __restrict__ mb1,
    const float* __restrict__ mw2, const float* __restrict__ mb2,
    float* __restrict__ o1, float* __restrict__ o2, int obase) {
  int oc = blockIdx.y + obase;
  const float* ao = oc ? ao2 : ao1;
  float* dst      = oc ? o2  : o1;
  __shared__ __align__(16) float wps[1024];
  __shared__ __align__(16) float w1s[2048];
  __shared__ __align__(16) float w2s[2048];
  __shared__ float bps[32], b1s[64], b2s[32], gs[32], bs[32], as[32], bbs[32];
  int t = threadIdx.x;
  for (int i = t; i < 1024; i += 256) wps[i] = wp[i];
  for (int i = t; i < 2048; i += 256) { w1s[i] = mw1[i]; w2s[i] = mw2[i]; }
  if (t < 64) b1s[t] = mb1[t];
  if (t < 32) {
    bps[t] = bp[t]; b2s[t] = mb2[t]; gs[t] = n2g[t]; bs[t] = n2b[t];
    float s = 0.f, ss = 0.f;
#pragma unroll
    for (int k = 0; k < 16; k++) { s += part[t*16+k]; ss += part[512 + t*16+k]; }
    float m = s * (1.f/65536.f);
    float var = ss * (1.f/65536.f) - m*m;
    float a = rsqrtf(var + 1e-5f) * ig[t];
    as[t] = a; bbs[t] = ib[t] - m*a;
  }
  __syncthreads();
  int p = blockIdx.x*256 + t;
  float acc[32];
#pragma unroll
  for (int j = 0; j < 32; j++) acc[j] = bps[j];
#pragma unroll
  for (int c = 0; c < 32; c++) {
    float vc = ao[c*HW+p];
    const float4* w4 = (const float4*)&wps[c*32];
#pragma unroll
    for (int j4 = 0; j4 < 8; j4++) {
      float4 w = w4[j4];
      acc[j4*4+0] += vc*w.x; acc[j4*4+1] += vc*w.y;
      acc[j4*4+2] += vc*w.z; acc[j4*4+3] += vc*w.w;
    }
  }
  if (oc == 0) {
#pragma unroll
    for (int j = 0; j < 32; j++) acc[j] += x[j*HW+p];
  } else {
#pragma unroll
    for (int j = 0; j < 32; j++) acc[j] += t4[j*HW+p]*as[j] + bbs[j];
  }
  float s = 0.f;
#pragma unroll
  for (int j = 0; j < 32; j++) s += acc[j];
  float m = s * 0.03125f;
  float ss = 0.f;
#pragma unroll
  for (int j = 0; j < 32; j++) { float d = acc[j]-m; ss += d*d; }
  float rs = rsqrtf(ss*0.03125f + 1e-5f);
  float r[32];
#pragma unroll
  for (int j = 0; j < 32; j++) r[j] = b2s[j];
#pragma unroll 1
  for (int half = 0; half < 2; half++) {
    float h[32];
#pragma unroll
    for (int k = 0; k < 32; k++) h[k] = b1s[half*32 + k];
#pragma unroll
    for (int c = 0; c < 32; c++) {
      float ln = (acc[c] - m) * rs * gs[c] + bs[c];
      const float4* w4 = (const float4*)&w1s[c*64 + half*32];
#pragma unroll
      for (int k4 = 0; k4 < 8; k4++) {
        float4 w = w4[k4];
        h[k4*4+0] += ln*w.x; h[k4*4+1] += ln*w.y; h[k4*4+2] += ln*w.z; h[k4*4+3] += ln*w.w;
      }
    }
#pragma unroll
    for (int k = 0; k < 32; k++) {
      float xx = h[k];
      float u = 0.7978845608f * (xx + 0.044715f*xx*xx*xx);
      float th = 1.f - 2.f/(1.f + __expf(2.f*u));
      h[k] = 0.5f * xx * (1.f + th);
    }
#pragma unroll
    for (int k = 0; k < 32; k++) {
      float hk = h[k];
      const float4* w4 = (const float4*)&w2s[(half*32 + k)*32];
#pragma unroll
      for (int j4 = 0; j4 < 8; j4++) {
        float4 w = w4[j4];
        r[j4*4+0] += hk*w.x; r[j4*4+1] += hk*w.y; r[j4*4+2] += hk*w.z; r[j4*4+3] += hk*w.w;
      }
    }
  }
#pragma unroll
  for (int j = 0; j < 32; j++) dst[j*HW + p] = acc[j] + r[j];
}

// ---------------- final: out = o1 + o2 + x (o1 aliases out) ----------------
__global__ __launch_bounds__(256) void k_final(
    const float* o1, const float* __restrict__ o2,
    const float* __restrict__ x, float* out) {
  int i = blockIdx.x*256 + threadIdx.x;
  float4 a = ((const float4*)o1)[i];
  float4 b = ((const float4*)o2)[i];
  float4 c = ((const float4*)x)[i];
  float4 r;
  r.x = a.x + b.x + c.x; r.y = a.y + b.y + c.y;
  r.z = a.z + b.z + c.z; r.w = a.w + b.w + c.w;
  ((float4*)out)[i] = r;
}

extern "C" void kernel_launch(void* const* d_in, const int* in_sizes, int n_in,
                              void* d_out, int out_size, void* d_ws, size_t ws_size,
                              hipStream_t stream) {
  const float* x    = (const float*)d_in[0];
  const float* depth= (const float*)d_in[1];
  const int*   rpi  = (const int*)d_in[2];
  const float* cw1  = (const float*)d_in[3],  *cb1 = (const float*)d_in[4];
  const float* cw2  = (const float*)d_in[5],  *cb2 = (const float*)d_in[6];
  const float* cw3  = (const float*)d_in[7],  *cb3 = (const float*)d_in[8];
  const float* cw4  = (const float*)d_in[9],  *cb4 = (const float*)d_in[10];
  const float* in_g = (const float*)d_in[11], *in_b = (const float*)d_in[12];
  const float* n1g  = (const float*)d_in[13], *n1b = (const float*)d_in[14];
  const float* wq   = (const float*)d_in[15], *bq  = (const float*)d_in[16];
  const float* wkv  = (const float*)d_in[17], *bkv = (const float*)d_in[18];
  const float* rpb  = (const float*)d_in[19];
  const float* wp   = (const float*)d_in[20], *bp  = (const float*)d_in[21];
  const float* n2g  = (const float*)d_in[22], *n2b = (const float*)d_in[23];
  const float* mw1  = (const float*)d_in[24], *mb1 = (const float*)d_in[25];
  const float* mw2  = (const float*)d_in[26], *mb2 = (const float*)d_in[27];

  float* W   = (float*)d_ws;
  float* o1  = (float*)d_out;

  bool big = ws_size >= (size_t)85100000;   // merged path needs ~85.07 MB

  if (big) {
    float* t4    = W;                    // 2M floats
    float* q1    = W + 2097152;
    float* q2    = W + 4194304;          // t3 aliases first 1M
    float* kv1   = W + 6291456;          // 4M
    float* kv2   = W + 10485760;         // 4M
    float* ao1   = W + 14680064;         // t2 aliases first 1M
    float* ao2   = W + 16777216;
    float* o2    = W + 18874368;
    float* biasT = W + 20971520;         // 294912
    float* part  = W + 21266432;         // 1024
    float* t2 = ao1, *t3 = q2;

    k_misc   <<<dim3(1152,8), 256, 0, stream>>>(depth, cw1, cb1, cw2, cb2, t2,
                                                rpi, rpb, biasT,
                                                x, t4, part, in_g, in_b, n1g, n1b,
                                                wq, bq, wkv, bkv, q1, kv1, q2, kv2);
    k_conv3  <<<dim3(256,4), 256, 0, stream>>>(t2, cw3, cb3, t3);
    k_conv4  <<<dim3(256,4), 256, 0, stream>>>(t3, cw4, cb4, t4);
    k_instats1<<<512, 256, 0, stream>>>(t4, part);
    k_lnmmB  <<<dim3(256,6), 256, 0, stream>>>(x, t4, part, in_g, in_b, n1g, n1b,
                                               wq, bq, wkv, bkv, q1, kv1, q2, kv2, 6);
    k_attn   <<<dim3(512,2), 256, 0, stream>>>(q1, kv1, ao1, q2, kv2, ao2, biasT);
    k_projmlp<<<dim3(256,2), 256, 0, stream>>>(ao1, ao2, x, t4, part, in_g, in_b,
                                               wp, bp, n2g, n2b, mw1, mb1, mw2, mb2,
                                               o1, o2, 0);
    k_final  <<<2048, 256, 0, stream>>>(o1, o2, x, o1);
  } else {
    // serial fallback, ~51.5 MB
    float* t4    = W;
    float* q1    = W + 2097152;
    float* kv1   = W + 4194304;          // 4M
    float* ao1   = W + 8388608;          // t2 aliases first 1M
    float* o2    = W + 10485760;         // t3 aliases first 1M
    float* biasT = W + 12582912;
    float* part  = W + 12877824;
    float* t2 = ao1, *t3 = o2;

    // misc: stem + bias + q1 halves (roles 0,1)
    k_misc   <<<dim3(1152,4), 256, 0, stream>>>(depth, cw1, cb1, cw2, cb2, t2,
                                                rpi, rpb, biasT,
                                                x, t4, part, in_g, in_b, n1g, n1b,
                                                wq, bq, wkv, bkv, q1, kv1, q1, kv1);
    k_conv3  <<<dim3(256,4), 256, 0, stream>>>(t2, cw3, cb3, t3);
    k_conv4  <<<dim3(256,4), 256, 0, stream>>>(t3, cw4, cb4, t4);
    k_instats1<<<512, 256, 0, stream>>>(t4, part);
    // ocab1 kv = IN(t4) side: roles 8..11 -> kv1
    k_lnmmB  <<<dim3(256,4), 256, 0, stream>>>(x, t4, part, in_g, in_b, n1g, n1b,
                                               wq, bq, wkv, bkv, q1, kv1, q1, kv1, 8);
    k_attn   <<<dim3(512,1), 256, 0, stream>>>(q1, kv1, ao1, q1, kv1, ao1, biasT);
    k_projmlp<<<dim3(256,1), 256, 0, stream>>>(ao1, ao1, x, t4, part, in_g, in_b,
                                               wp, bp, n2g, n2b, mw1, mb1, mw2, mb2,
                                               o1, o2, 0);
    // ocab2: q2 = roles 6,7 (dst q2->q1 buf), kv2 = roles 2..5 (dst kv2->kv1 buf)
    k_lnmmB  <<<dim3(256,6), 256, 0, stream>>>(x, t4, part, in_g, in_b, n1g, n1b,
                                               wq, bq, wkv, bkv, q1, kv1, q1, kv1, 2);
    k_attn   <<<dim3(512,1), 256, 0, stream>>>(q1, kv1, ao1, q1, kv1, ao1, biasT);
    k_projmlp<<<dim3(256,1), 256, 0, stream>>>(ao1, ao1, x, t4, part, in_g, in_b,
                                               wp, bp, n2g, n2b, mw1, mb1, mw2, mb2,
                                               o1, o2, 1);
    k_final  <<<2048, 256, 0, stream>>>(o1, o2, x, o1);
  }
}

// Round 9
// 258.877 us; speedup vs baseline: 2.6188x; 1.0803x over previous
//
#include <hip/hip_runtime.h>
#include <hip/hip_bf16.h>

#define HW 65536
#define KPAD 584   // Vt row stride (bf16): 1168B rows, 16B-aligned

typedef __attribute__((ext_vector_type(8))) short bf8;
typedef __attribute__((ext_vector_type(4))) float f4;

__device__ __forceinline__ unsigned short f2b(float x) {   // RNE float->bf16
  unsigned int u = __float_as_uint(x);
  unsigned int r = (u + 0x7fff + ((u >> 16) & 1)) >> 16;
  return (unsigned short)r;
}
__device__ __forceinline__ unsigned int pk2(float lo, float hi) {  // trunc pack 2xbf16
  return (__float_as_uint(hi) & 0xffff0000u) | (__float_as_uint(lo) >> 16);
}
__device__ __forceinline__ float ex2(float x) { return __builtin_amdgcn_exp2f(x); }

// ================= device bodies =================
__device__ __forceinline__ void stem_front_body(
    int bx, int t, const float* __restrict__ depth,
    const float* __restrict__ cw1, const float* __restrict__ cb1,
    const float* __restrict__ cw2, const float* __restrict__ cb2,
    float* __restrict__ t2) {
  int p = bx * 256 + t;
  int y = p >> 8, x = p & 255;
  float in9[9];
#pragma unroll
  for (int ky = 0; ky < 3; ky++)
#pragma unroll
    for (int kx = 0; kx < 3; kx++) {
      int yy = y + ky - 1, xx = x + kx - 1;
      bool ok = ((unsigned)yy < 256u) && ((unsigned)xx < 256u);
      in9[ky*3+kx] = ok ? depth[yy*256+xx] : 0.f;
    }
  float t1[8];
#pragma unroll
  for (int o = 0; o < 8; o++) {
    float s = cb1[o];
#pragma unroll
    for (int i = 0; i < 9; i++) s += in9[i] * cw1[o*9+i];
    t1[o] = fmaxf(s, 0.f);
  }
#pragma unroll
  for (int o = 0; o < 16; o++) {
    float s = cb2[o];
#pragma unroll
    for (int ci = 0; ci < 8; ci++) s += t1[ci] * cw2[o*8+ci];
    t2[o*HW + p] = fmaxf(s, 0.f);
  }
}

// bias layout per (hd,qt): [kb=key/4][q16][r=key&3]; pre-scaled by 1/ln2 with -8 shift
__device__ __forceinline__ void bias_body(
    int bx, int t, const int* __restrict__ rpi,
    const float* __restrict__ rpb, float* __restrict__ biasT) {
  int idx = bx*256 + t;        // 1152*256 = 294912 exact
  int hd = idx / 147456;
  int rem = idx - hd*147456;
  int qt = rem / 9216;
  int r2 = rem - qt*9216;
  int kb = r2 >> 6;
  int q16 = (r2 >> 2) & 15;
  int r = r2 & 3;
  int key = kb*4 + r;
  int qq = qt*16 + q16;
  biasT[idx] = (rpb[rpi[qq*576 + key]*2 + hd] - 8.0f) * 1.44269504f;
}

// 16-output LN(+IN) matmul slab.
// roles: 0/1: q1 = LN(x)@wq cols 0/16        2..5: kv2 = LN(x)@wkv cols 16c
//        6/7: q2 = LN(IN(t4))@wq cols 0/16   8..11: kv1 = LN(IN(t4))@wkv cols 16c
__device__ __forceinline__ void lnmm16_body(
    int role, int bx, int t,
    float* ws, float* gs, float* bs, float* b2s, float* as, float* bbs,
    const float* __restrict__ x, const float* __restrict__ t4,
    const float* __restrict__ part,
    const float* __restrict__ ig, const float* __restrict__ ib,
    const float* __restrict__ n1g, const float* __restrict__ n1b,
    const float* __restrict__ wq, const float* __restrict__ bq,
    const float* __restrict__ wkv, const float* __restrict__ bkv,
    float* q1, float* kv1, float* q2, float* kv2) {
  const float *src, *wm, *bo; float* dst;
  int wstride, wcol; bool ain;
  if (role < 6) { src = x;  ain = false; } else { src = t4; ain = true; }
  switch (role) {
    default:
    case 0:  wm=wq;  wstride=32; wcol=0;  bo=bq;  dst=q1;               break;
    case 1:  wm=wq;  wstride=32; wcol=16; bo=bq;  dst=q1+16*HW;         break;
    case 2: case 3: case 4: case 5:
             wm=wkv; wstride=64; wcol=16*(role-2); bo=bkv; dst=kv2+16*(role-2)*HW; break;
    case 6:  wm=wq;  wstride=32; wcol=0;  bo=bq;  dst=q2;               break;
    case 7:  wm=wq;  wstride=32; wcol=16; bo=bq;  dst=q2+16*HW;         break;
    case 8: case 9: case 10: case 11:
             wm=wkv; wstride=64; wcol=16*(role-8); bo=bkv; dst=kv1+16*(role-8)*HW; break;
  }
  for (int i = t; i < 512; i += 256) ws[i] = wm[(i>>4)*wstride + wcol + (i&15)];
  if (t < 16) b2s[t] = bo[wcol + t];
  if (t < 32) {
    gs[t] = n1g[t]; bs[t] = n1b[t];
    if (ain) {
      float s = 0.f, ss = 0.f;
#pragma unroll
      for (int k = 0; k < 16; k++) { s += part[t*16+k]; ss += part[512 + t*16+k]; }
      float m = s * (1.f/65536.f);
      float var = ss * (1.f/65536.f) - m*m;
      float a = rsqrtf(var + 1e-5f) * ig[t];
      as[t] = a; bbs[t] = ib[t] - m*a;
    }
  }
  __syncthreads();
  int p = bx*256 + t;
  float v[32]; float s = 0.f;
  if (ain) {
#pragma unroll
    for (int c = 0; c < 32; c++) { v[c] = src[c*HW+p]*as[c] + bbs[c]; s += v[c]; }
  } else {
#pragma unroll
    for (int c = 0; c < 32; c++) { v[c] = src[c*HW+p]; s += v[c]; }
  }
  float m = s * 0.03125f;
  float ss = 0.f;
#pragma unroll
  for (int c = 0; c < 32; c++) { float d = v[c]-m; ss += d*d; }
  float rs = rsqrtf(ss*0.03125f + 1e-5f);
  float acc[16];
#pragma unroll
  for (int j = 0; j < 16; j++) acc[j] = b2s[j];
#pragma unroll
  for (int c = 0; c < 32; c++) {
    float ln = (v[c]-m)*rs*gs[c] + bs[c];
    const float4* w4 = (const float4*)&ws[c*16];
#pragma unroll
    for (int j4 = 0; j4 < 4; j4++) {
      float4 w = w4[j4];
      acc[j4*4+0] += ln*w.x; acc[j4*4+1] += ln*w.y;
      acc[j4*4+2] += ln*w.z; acc[j4*4+3] += ln*w.w;
    }
  }
#pragma unroll
  for (int j = 0; j < 16; j++) dst[j*HW+p] = acc[j];
}

// ================= kernels =================
// flat mega-launch: [0,256) stem | [256,1408) bias | [1408, 1408+nln*256) lnmm16 roles
__global__ __launch_bounds__(256) void k_misc(
    const float* __restrict__ depth,
    const float* __restrict__ cw1, const float* __restrict__ cb1,
    const float* __restrict__ cw2, const float* __restrict__ cb2,
    float* __restrict__ t2,
    const int* __restrict__ rpi, const float* __restrict__ rpb, float* __restrict__ biasT,
    const float* __restrict__ x, const float* __restrict__ t4, const float* __restrict__ part,
    const float* __restrict__ ig, const float* __restrict__ ib,
    const float* __restrict__ n1g, const float* __restrict__ n1b,
    const float* __restrict__ wq, const float* __restrict__ bq,
    const float* __restrict__ wkv, const float* __restrict__ bkv,
    float* q1, float* kv1, float* q2, float* kv2) {
  __shared__ __align__(16) float ws[512];
  __shared__ float gs[32], bs[32], b2s[16], as[32], bbs[32];
  int id = blockIdx.x, t = threadIdx.x;
  if (id < 256) { stem_front_body(id, t, depth, cw1, cb1, cw2, cb2, t2); return; }
  if (id < 1408) { bias_body(id - 256, t, rpi, rpb, biasT); return; }
  int r = id - 1408;
  lnmm16_body(r >> 8, r & 255, t, ws, gs, bs, b2s, as, bbs,
              x, t4, part, ig, ib, n1g, n1b, wq, bq, wkv, bkv, q1, kv1, q2, kv2);
}

__global__ __launch_bounds__(256) void k_lnmmB(
    const float* __restrict__ x, const float* __restrict__ t4, const float* __restrict__ part,
    const float* __restrict__ ig, const float* __restrict__ ib,
    const float* __restrict__ n1g, const float* __restrict__ n1b,
    const float* __restrict__ wq, const float* __restrict__ bq,
    const float* __restrict__ wkv, const float* __restrict__ bkv,
    float* q1, float* kv1, float* q2, float* kv2, int ybase) {
  __shared__ __align__(16) float ws[512];
  __shared__ float gs[32], bs[32], b2s[16], as[32], bbs[32];
  lnmm16_body(ybase + blockIdx.y, blockIdx.x, threadIdx.x, ws, gs, bs, b2s, as, bbs,
              x, t4, part, ig, ib, n1g, n1b, wq, bq, wkv, bkv, q1, kv1, q2, kv2);
}

__global__ __launch_bounds__(256) void k_conv3(
    const float* __restrict__ t2, const float* __restrict__ cw3,
    const float* __restrict__ cb3, float* __restrict__ t3) {
  int t = threadIdx.x;
  int p = blockIdx.x*256 + t;
  int og = blockIdx.y;
  int y = p >> 8, x = p & 255;
  float acc[4];
#pragma unroll
  for (int o = 0; o < 4; o++) acc[o] = cb3[og*4+o];
#pragma unroll 1
  for (int tap = 0; tap < 9; tap++) {
    int ky = tap/3 - 1, kx = tap - (tap/3)*3 - 1;
    int yy = y+ky, xx = x+kx;
    bool ok = ((unsigned)yy < 256u) && ((unsigned)xx < 256u);
    int pp = yy*256+xx;
#pragma unroll
    for (int ci = 0; ci < 16; ci++) {
      float v = ok ? t2[ci*HW+pp] : 0.f;
#pragma unroll
      for (int o = 0; o < 4; o++)
        acc[o] += v * cw3[(og*4+o)*144 + ci*9 + tap];   // uniform -> s_load
    }
  }
#pragma unroll
  for (int o = 0; o < 4; o++) t3[(og*4+o)*HW+p] = fmaxf(acc[o], 0.f);
}

// conv4 split over y: 8 outputs per block -> 1024 blocks
__global__ __launch_bounds__(256) void k_conv4(
    const float* __restrict__ t3, const float* __restrict__ cw4,
    const float* __restrict__ cb4, float* __restrict__ t4) {
  int t = threadIdx.x;
  int p = blockIdx.x*256 + t;
  int og = blockIdx.y;           // 8 outputs per group
  float v[16];
#pragma unroll
  for (int ci = 0; ci < 16; ci++) v[ci] = t3[ci*HW+p];
#pragma unroll
  for (int o = 0; o < 8; o++) {
    int oo = og*8 + o;
    float s = cb4[oo];
#pragma unroll
    for (int ci = 0; ci < 16; ci++) s += v[ci]*cw4[oo*16+ci];
    t4[oo*HW+p] = s;
  }
}

__global__ __launch_bounds__(256) void k_instats1(const float* __restrict__ t4,
                                                  float* __restrict__ part) {
  int c = blockIdx.x >> 4, seg = blockIdx.x & 15;   // 512 blocks
  const float4* src = (const float4*)(t4 + c*HW + seg*4096);
  float s = 0.f, ss = 0.f;
  for (int i = threadIdx.x; i < 1024; i += 256) {
    float4 v = src[i];
    s  += v.x + v.y + v.z + v.w;
    ss += v.x*v.x + v.y*v.y + v.z*v.z + v.w*v.w;
  }
#pragma unroll
  for (int off = 32; off > 0; off >>= 1) {
    s  += __shfl_down(s, off, 64);
    ss += __shfl_down(ss, off, 64);
  }
  __shared__ float sh[8];
  int wid = threadIdx.x >> 6;
  if ((threadIdx.x & 63) == 0) { sh[wid] = s; sh[4+wid] = ss; }
  __syncthreads();
  if (threadIdx.x == 0) {
    part[blockIdx.x]       = sh[0]+sh[1]+sh[2]+sh[3];
    part[512 + blockIdx.x] = sh[4]+sh[5]+sh[6]+sh[7];
  }
}

// ---------------- MFMA attention: S^T form, 4 q-tiles, register-Q, 4 blocks/CU ----------------
__global__ __launch_bounds__(256, 4) void k_attn(
    const float* __restrict__ qA, const float* __restrict__ kvA, float* __restrict__ aoA,
    const float* __restrict__ qB, const float* __restrict__ kvB, float* __restrict__ aoB,
    const float* __restrict__ biasT) {
  __shared__ __align__(16) unsigned short Ks[576*16];   // [key][d]  18432B
  __shared__ __align__(16) unsigned short Vt[16*KPAD];  // [d][key-permuted] 18688B

  const float* q  = blockIdx.y ? qB  : qA;
  const float* kv = blockIdx.y ? kvB : kvA;
  float* ao       = blockIdx.y ? aoB : aoA;

  // XCD swizzle: contiguous window stripes per XCD for kv-overlap L2 reuse
  int id = blockIdx.x;                       // 0..511
  int lin = ((id & 7) << 6) | (id >> 3);
  int wi = lin >> 1, hd = lin & 1;
  int wy = wi >> 4, wx = wi & 15;
  int t = threadIdx.x;
  int by = wy*16 - 4, bx = wx*16 - 4;
  int kbase = hd*16*HW, vbase = (32 + hd*16)*HW;

  int wave = t >> 6, lane = t & 63;
  int quad = lane >> 4, l16 = lane & 15;
  const bf8 zero8 = {0,0,0,0,0,0,0,0};

  // --- Q fragments: direct register gather (no LDS, no barrier needed)
  bf8 qf[4];
#pragma unroll
  for (int qi = 0; qi < 4; qi++) {
    int qt = wave*4 + qi;
    if (quad < 2) {
      int prow = (wy*16 + qt)*256 + wx*16 + l16;
      unsigned short qtmp[8];
#pragma unroll
      for (int j = 0; j < 8; j++)
        qtmp[j] = f2b(q[(hd*16 + quad*8 + j)*HW + prow] * 0.360673503f); // 0.25/ln2
      qf[qi] = *(const bf8*)qtmp;
    } else {
      qf[qi] = zero8;
    }
  }

  // --- stage K (row-major) and V (transposed, slot-permuted)
  for (int e = t; e < 576; e += 256) {
    int dy = e / 24, dx = e - dy*24;
    int yy = by + dy, xx = bx + dx;
    bool ok = ((unsigned)yy < 256u) && ((unsigned)xx < 256u);
    int pp = yy*256 + xx;
    int off = e & 31;
    int ppos = ((off & 12) << 1) + ((off >> 4) << 2) + (off & 3);
    int vcol = (e & ~31) + ppos;
    unsigned short tk[16];
#pragma unroll
    for (int i = 0; i < 16; i++) {
      float kvl = ok ? kv[kbase + i*HW + pp] : 0.f;
      float vvl = ok ? kv[vbase + i*HW + pp] : 0.f;
      tk[i] = f2b(kvl);
      Vt[i*KPAD + vcol] = f2b(vvl);
    }
    *(uint4*)&Ks[e*16]     = *(uint4*)&tk[0];
    *(uint4*)&Ks[e*16 + 8] = *(uint4*)&tk[8];
  }
  __syncthreads();

  f4 oacc[4];
  float lr[4];
  const float* bb[4];
#pragma unroll
  for (int qi = 0; qi < 4; qi++) {
    int qt = wave*4 + qi;
    oacc[qi] = (f4){0.f,0.f,0.f,0.f};
    lr[qi] = 0.f;
    bb[qi] = biasT + (hd*16 + qt)*9216 + quad*64 + l16*4;
  }

#pragma unroll 2
  for (int kt2 = 0; kt2 < 18; kt2++) {
    int k0 = kt2 * 32;
    bf8 kf0 = zero8, kf1 = zero8;
    if (quad < 2) {
      kf0 = *(const bf8*)&Ks[(k0 + l16)*16 + quad*8];
      kf1 = *(const bf8*)&Ks[(k0 + 16 + l16)*16 + quad*8];
    }
    bf8 vf = *(const bf8*)&Vt[l16*KPAD + k0 + quad*8];
#pragma unroll
    for (int qi = 0; qi < 4; qi++) {
      f4 b0 = *(const f4*)&bb[qi][k0*16];
      f4 b1 = *(const f4*)&bb[qi][(k0+16)*16];
      f4 s0 = __builtin_amdgcn_mfma_f32_16x16x32_bf16(kf0, qf[qi], b0, 0, 0, 0);
      f4 s1 = __builtin_amdgcn_mfma_f32_16x16x32_bf16(kf1, qf[qi], b1, 0, 0, 0);
      float p0[4], p1[4];
#pragma unroll
      for (int r = 0; r < 4; r++) {
        p0[r] = ex2(s0[r]);
        p1[r] = ex2(s1[r]);
        lr[qi] += p0[r] + p1[r];
      }
      union { unsigned int u[4]; bf8 v; } P;
      P.u[0] = pk2(p0[0], p0[1]); P.u[1] = pk2(p0[2], p0[3]);
      P.u[2] = pk2(p1[0], p1[1]); P.u[3] = pk2(p1[2], p1[3]);
      oacc[qi] = __builtin_amdgcn_mfma_f32_16x16x32_bf16(P.v, vf, oacc[qi], 0, 0, 0);
    }
  }
#pragma unroll
  for (int qi = 0; qi < 4; qi++) {
    lr[qi] += __shfl_xor(lr[qi], 16, 64);
    lr[qi] += __shfl_xor(lr[qi], 32, 64);
  }
#pragma unroll
  for (int qi = 0; qi < 4; qi++) {
    int qt = wave*4 + qi;
#pragma unroll
    for (int r = 0; r < 4; r++) {
      float lv = __shfl(lr[qi], quad*4 + r, 64);
      int qw = qt*16 + quad*4 + r;
      ao[(hd*16 + l16)*HW + (wy*16 + (qw >> 4))*256 + wx*16 + (qw & 15)] = oacc[qi][r] / lv;
    }
  }
}

// ---------------- proj+shortcut+LN+MLP, ONE ocab per block (proven, no spill) ----------------
__global__ __launch_bounds__(256) void k_projmlp(
    const float* __restrict__ ao1, const float* __restrict__ ao2,
    const float* __restrict__ x, const float* __restrict__ t4,
    const float* __restrict__ part,
    const float* __restrict__ ig, const float* __restrict__ ib,
    const float* __restrict__ wp, const float* __restrict__ bp,
    const float* __restrict__ n2g, const float* __restrict__ n2b,
    const float* __restrict__ mw1, const float* __restrict__ mb1,
    const float* __restrict__ mw2, const float* __restrict__ mb2,
    float* __restrict__ o1, float* __restrict__ o2, int obase) {
  int oc = blockIdx.y + obase;
  const float* ao = oc ? ao2 : ao1;
  float* dst      = oc ? o2  : o1;
  __shared__ __align__(16) float wps[1024];
  __shared__ __align__(16) float w1s[2048];
  __shared__ __align__(16) float w2s[2048];
  __shared__ float bps[32], b1s[64], b2s[32], gs[32], bs[32], as[32], bbs[32];
  int t = threadIdx.x;
  for (int i = t; i < 1024; i += 256) wps[i] = wp[i];
  for (int i = t; i < 2048; i += 256) { w1s[i] = mw1[i]; w2s[i] = mw2[i]; }
  if (t < 64) b1s[t] = mb1[t];
  if (t < 32) {
    bps[t] = bp[t]; b2s[t] = mb2[t]; gs[t] = n2g[t]; bs[t] = n2b[t];
    float s = 0.f, ss = 0.f;
#pragma unroll
    for (int k = 0; k < 16; k++) { s += part[t*16+k]; ss += part[512 + t*16+k]; }
    float m = s * (1.f/65536.f);
    float var = ss * (1.f/65536.f) - m*m;
    float a = rsqrtf(var + 1e-5f) * ig[t];
    as[t] = a; bbs[t] = ib[t] - m*a;
  }
  __syncthreads();
  int p = blockIdx.x*256 + t;
  float acc[32];
#pragma unroll
  for (int j = 0; j < 32; j++) acc[j] = bps[j];
#pragma unroll
  for (int c = 0; c < 32; c++) {
    float vc = ao[c*HW+p];
    const float4* w4 = (const float4*)&wps[c*32];
#pragma unroll
    for (int j4 = 0; j4 < 8; j4++) {
      float4 w = w4[j4];
      acc[j4*4+0] += vc*w.x; acc[j4*4+1] += vc*w.y;
      acc[j4*4+2] += vc*w.z; acc[j4*4+3] += vc*w.w;
    }
  }
  if (oc == 0) {
#pragma unroll
    for (int j = 0; j < 32; j++) acc[j] += x[j*HW+p];
  } else {
#pragma unroll
    for (int j = 0; j < 32; j++) acc[j] += t4[j*HW+p]*as[j] + bbs[j];
  }
  float s = 0.f;
#pragma unroll
  for (int j = 0; j < 32; j++) s += acc[j];
  float m = s * 0.03125f;
  float ss = 0.f;
#pragma unroll
  for (int j = 0; j < 32; j++) { float d = acc[j]-m; ss += d*d; }
  float rs = rsqrtf(ss*0.03125f + 1e-5f);
  float r[32];
#pragma unroll
  for (int j = 0; j < 32; j++) r[j] = b2s[j];
#pragma unroll 1
  for (int half = 0; half < 2; half++) {
    float h[32];
#pragma unroll
    for (int k = 0; k < 32; k++) h[k] = b1s[half*32 + k];
#pragma unroll
    for (int c = 0; c < 32; c++) {
      float ln = (acc[c] - m) * rs * gs[c] + bs[c];
      const float4* w4 = (const float4*)&w1s[c*64 + half*32];
#pragma unroll
      for (int k4 = 0; k4 < 8; k4++) {
        float4 w = w4[k4];
        h[k4*4+0] += ln*w.x; h[k4*4+1] += ln*w.y; h[k4*4+2] += ln*w.z; h[k4*4+3] += ln*w.w;
      }
    }
#pragma unroll
    for (int k = 0; k < 32; k++) {
      float xx = h[k];
      float u = 0.7978845608f * (xx + 0.044715f*xx*xx*xx);
      float th = 1.f - 2.f/(1.f + __expf(2.f*u));
      h[k] = 0.5f * xx * (1.f + th);
    }
#pragma unroll
    for (int k = 0; k < 32; k++) {
      float hk = h[k];
      const float4* w4 = (const float4*)&w2s[(half*32 + k)*32];
#pragma unroll
      for (int j4 = 0; j4 < 8; j4++) {
        float4 w = w4[j4];
        r[j4*4+0] += hk*w.x; r[j4*4+1] += hk*w.y; r[j4*4+2] += hk*w.z; r[j4*4+3] += hk*w.w;
      }
    }
  }
#pragma unroll
  for (int j = 0; j < 32; j++) dst[j*HW + p] = acc[j] + r[j];
}

// ---------------- final: out = o1 + o2 + x (o1 aliases out) ----------------
__global__ __launch_bounds__(256) void k_final(
    const float* o1, const float* __restrict__ o2,
    const float* __restrict__ x, float* out) {
  int i = blockIdx.x*256 + threadIdx.x;
  float4 a = ((const float4*)o1)[i];
  float4 b = ((const float4*)o2)[i];
  float4 c = ((const float4*)x)[i];
  float4 r;
  r.x = a.x + b.x + c.x; r.y = a.y + b.y + c.y;
  r.z = a.z + b.z + c.z; r.w = a.w + b.w + c.w;
  ((float4*)out)[i] = r;
}

extern "C" void kernel_launch(void* const* d_in, const int* in_sizes, int n_in,
                              void* d_out, int out_size, void* d_ws, size_t ws_size,
                              hipStream_t stream) {
  const float* x    = (const float*)d_in[0];
  const float* depth= (const float*)d_in[1];
  const int*   rpi  = (const int*)d_in[2];
  const float* cw1  = (const float*)d_in[3],  *cb1 = (const float*)d_in[4];
  const float* cw2  = (const float*)d_in[5],  *cb2 = (const float*)d_in[6];
  const float* cw3  = (const float*)d_in[7],  *cb3 = (const float*)d_in[8];
  const float* cw4  = (const float*)d_in[9],  *cb4 = (const float*)d_in[10];
  const float* in_g = (const float*)d_in[11], *in_b = (const float*)d_in[12];
  const float* n1g  = (const float*)d_in[13], *n1b = (const float*)d_in[14];
  const float* wq   = (const float*)d_in[15], *bq  = (const float*)d_in[16];
  const float* wkv  = (const float*)d_in[17], *bkv = (const float*)d_in[18];
  const float* rpb  = (const float*)d_in[19];
  const float* wp   = (const float*)d_in[20], *bp  = (const float*)d_in[21];
  const float* n2g  = (const float*)d_in[22], *n2b = (const float*)d_in[23];
  const float* mw1  = (const float*)d_in[24], *mb1 = (const float*)d_in[25];
  const float* mw2  = (const float*)d_in[26], *mb2 = (const float*)d_in[27];

  float* W   = (float*)d_ws;
  float* o1  = (float*)d_out;

  bool big = ws_size >= (size_t)85100000;   // merged path needs ~85.07 MB

  if (big) {
    float* t4    = W;                    // 2M floats
    float* q1    = W + 2097152;
    float* q2    = W + 4194304;          // t3 aliases first 1M
    float* kv1   = W + 6291456;          // 4M
    float* kv2   = W + 10485760;         // 4M
    float* ao1   = W + 14680064;         // t2 aliases first 1M
    float* ao2   = W + 16777216;
    float* o2    = W + 18874368;
    float* biasT = W + 20971520;         // 294912
    float* part  = W + 21266432;         // 1024
    float* t2 = ao1, *t3 = q2;

    // flat misc: stem(256) + bias(1152) + lnmm roles 0..5 (q1, kv2) = 2944 blocks
    k_misc   <<<2944, 256, 0, stream>>>(depth, cw1, cb1, cw2, cb2, t2,
                                        rpi, rpb, biasT,
                                        x, t4, part, in_g, in_b, n1g, n1b,
                                        wq, bq, wkv, bkv, q1, kv1, q2, kv2);
    k_conv3  <<<dim3(256,4), 256, 0, stream>>>(t2, cw3, cb3, t3);
    k_conv4  <<<dim3(256,4), 256, 0, stream>>>(t3, cw4, cb4, t4);
    k_instats1<<<512, 256, 0, stream>>>(t4, part);
    k_lnmmB  <<<dim3(256,6), 256, 0, stream>>>(x, t4, part, in_g, in_b, n1g, n1b,
                                               wq, bq, wkv, bkv, q1, kv1, q2, kv2, 6);
    k_attn   <<<dim3(512,2), 256, 0, stream>>>(q1, kv1, ao1, q2, kv2, ao2, biasT);
    k_projmlp<<<dim3(256,2), 256, 0, stream>>>(ao1, ao2, x, t4, part, in_g, in_b,
                                               wp, bp, n2g, n2b, mw1, mb1, mw2, mb2,
                                               o1, o2, 0);
    k_final  <<<2048, 256, 0, stream>>>(o1, o2, x, o1);
  } else {
    // serial fallback, ~51.5 MB
    float* t4    = W;
    float* q1    = W + 2097152;
    float* kv1   = W + 4194304;          // 4M
    float* ao1   = W + 8388608;          // t2 aliases first 1M
    float* o2    = W + 10485760;         // t3 aliases first 1M
    float* biasT = W + 12582912;
    float* part  = W + 12877824;
    float* t2 = ao1, *t3 = o2;

    // flat misc: stem + bias + lnmm roles 0,1 (q1) = 1920 blocks
    k_misc   <<<1920, 256, 0, stream>>>(depth, cw1, cb1, cw2, cb2, t2,
                                        rpi, rpb, biasT,
                                        x, t4, part, in_g, in_b, n1g, n1b,
                                        wq, bq, wkv, bkv, q1, kv1, q1, kv1);
    k_conv3  <<<dim3(256,4), 256, 0, stream>>>(t2, cw3, cb3, t3);
    k_conv4  <<<dim3(256,4), 256, 0, stream>>>(t3, cw4, cb4, t4);
    k_instats1<<<512, 256, 0, stream>>>(t4, part);
    // ocab1 kv = IN(t4) side: roles 8..11 -> kv1
    k_lnmmB  <<<dim3(256,4), 256, 0, stream>>>(x, t4, part, in_g, in_b, n1g, n1b,
                                               wq, bq, wkv, bkv, q1, kv1, q1, kv1, 8);
    k_attn   <<<dim3(512,1), 256, 0, stream>>>(q1, kv1, ao1, q1, kv1, ao1, biasT);
    k_projmlp<<<dim3(256,1), 256, 0, stream>>>(ao1, ao1, x, t4, part, in_g, in_b,
                                               wp, bp, n2g, n2b, mw1, mb1, mw2, mb2,
                                               o1, o2, 0);
    // ocab2: kv2 roles 2..5 (dst kv2->kv1 buf), q2 roles 6,7 (dst q2->q1 buf)
    k_lnmmB  <<<dim3(256,6), 256, 0, stream>>>(x, t4, part, in_g, in_b, n1g, n1b,
                                               wq, bq, wkv, bkv, q1, kv1, q1, kv1, 2);
    k_attn   <<<dim3(512,1), 256, 0, stream>>>(q1, kv1, ao1, q1, kv1, ao1, biasT);
    k_projmlp<<<dim3(256,1), 256, 0, stream>>>(ao1, ao1, x, t4, part, in_g, in_b,
                                               wp, bp, n2g, n2b, mw1, mb1, mw2, mb2,
                                               o1, o2, 1);
    k_final  <<<2048, 256, 0, stream>>>(o1, o2, x, o1);
  }
}